// Round 1
// baseline (331.701 us; speedup 1.0000x reference)
//
#include <hip/hip_runtime.h>
#include <hip/hip_bf16.h>

// Problem constants
#define BB 2
#define TT 2048
#define NX 512
#define NH 4      // 2*H
#define HD 128
#define LL 64
#define KK 32
#define VH 256    // 2*hd

// ---------------------------------------------------------------------------
// Generic 64x64 f32 GEMM tile:  C[m,n] = sum_k A[m0+m, k] * Bw[n0+n, k]
// (both A and Bw row-major, reduction along fast axis). 256 threads, 4x4/thread.
// ---------------------------------------------------------------------------
__device__ __forceinline__ void gemm_tile64(const float* __restrict__ A, int lda,
                                            const float* __restrict__ Bw, int ldb,
                                            float* __restrict__ C, int ldc,
                                            int Kdim, int m0, int n0)
{
    __shared__ float As[64][17];
    __shared__ float Bs[64][17];
    const int tid = threadIdx.x;
    const int tx = tid & 15, ty = tid >> 4;
    float acc[4][4] = {};

    for (int k0 = 0; k0 < Kdim; k0 += 16) {
        const int flat = tid * 4;
        const int r = flat >> 4, c = flat & 15;
        const float4 av = *reinterpret_cast<const float4*>(&A[(size_t)(m0 + r) * lda + k0 + c]);
        const float4 bv = *reinterpret_cast<const float4*>(&Bw[(size_t)(n0 + r) * ldb + k0 + c]);
        __syncthreads();   // previous iteration's reads done
        As[r][c] = av.x; As[r][c + 1] = av.y; As[r][c + 2] = av.z; As[r][c + 3] = av.w;
        Bs[r][c] = bv.x; Bs[r][c + 1] = bv.y; Bs[r][c + 2] = bv.z; Bs[r][c + 3] = bv.w;
        __syncthreads();
        #pragma unroll
        for (int kk = 0; kk < 16; ++kk) {
            float a0 = As[ty * 4 + 0][kk], a1 = As[ty * 4 + 1][kk];
            float a2 = As[ty * 4 + 2][kk], a3 = As[ty * 4 + 3][kk];
            float b0 = Bs[tx * 4 + 0][kk], b1 = Bs[tx * 4 + 1][kk];
            float b2 = Bs[tx * 4 + 2][kk], b3 = Bs[tx * 4 + 3][kk];
            acc[0][0] += a0 * b0; acc[0][1] += a0 * b1; acc[0][2] += a0 * b2; acc[0][3] += a0 * b3;
            acc[1][0] += a1 * b0; acc[1][1] += a1 * b1; acc[1][2] += a1 * b2; acc[1][3] += a1 * b3;
            acc[2][0] += a2 * b0; acc[2][1] += a2 * b1; acc[2][2] += a2 * b2; acc[2][3] += a2 * b3;
            acc[3][0] += a3 * b0; acc[3][1] += a3 * b1; acc[3][2] += a3 * b2; acc[3][3] += a3 * b3;
        }
    }
    #pragma unroll
    for (int i = 0; i < 4; ++i)
        #pragma unroll
        for (int j = 0; j < 4; ++j)
            C[(size_t)(m0 + ty * 4 + i) * ldc + n0 + tx * 4 + j] = acc[i][j];
}

// QKV: q/k/v[i,n] = sum_c x[i,c] * w{q,k,v}[n,c]    (M=4096, N=512, K=512)
__global__ void k_gemm_qkv(const float* __restrict__ x,
                           const float* __restrict__ wq, const float* __restrict__ wk,
                           const float* __restrict__ wv,
                           float* __restrict__ q, float* __restrict__ k, float* __restrict__ v)
{
    const int m0 = blockIdx.x * 64;
    const int n0 = blockIdx.y * 64;
    const float* Bw = (blockIdx.z == 0) ? wq : (blockIdx.z == 1) ? wk : wv;
    float* C = (blockIdx.z == 0) ? q : (blockIdx.z == 1) ? k : v;
    gemm_tile64(x, NX, Bw, NX, C, NX, NX, m0, n0);
}

// Output: out[i,n] = sum_c ao[i,c] * wo[n,c]
__global__ void k_gemm_out(const float* __restrict__ ao, const float* __restrict__ wo,
                           float* __restrict__ out)
{
    gemm_tile64(ao, NX, wo, NX, out, NX, NX, blockIdx.x * 64, blockIdx.y * 64);
}

// lam / lam_init scalars
__global__ void k_prep(const float* __restrict__ lq1, const float* __restrict__ lk1,
                       const float* __restrict__ lq2, const float* __restrict__ lk2,
                       const int* __restrict__ lint, float* __restrict__ scal)
{
    const int tid = threadIdx.x;  // 64 threads = 1 wave
    float s1 = lq1[tid] * lk1[tid] + lq1[tid + 64] * lk1[tid + 64];
    float s2 = lq2[tid] * lk2[tid] + lq2[tid + 64] * lk2[tid + 64];
    for (int off = 32; off; off >>= 1) { s1 += __shfl_xor(s1, off); s2 += __shfl_xor(s2, off); }
    if (tid == 0) {
        float lam_init = 0.8f - 0.6f * expf(-0.3f * (float)lint[0]);
        float lam = expf(s1) - expf(s2) + lam_init;
        scal[0] = lam;
        scal[1] = lam_init;
    }
}

// Normalized landmark rows, scales folded in:
//   qn[b,h,l,:] = m1[h,l] * q[b,landmark[l],h-slice] / ||.||   (feeds w2)
//   kn[b,h,l,:] = m2[h,l] * k[b,landmark[l],h-slice] / ||.||   (feeds w1)
__global__ void k_norm_lm(const float* __restrict__ q, const float* __restrict__ k,
                          const float* __restrict__ m1, const float* __restrict__ m2,
                          const int* __restrict__ landmark,
                          float* __restrict__ qn, float* __restrict__ kn)
{
    const int idx = blockIdx.x;              // B*NH*L = 512 blocks
    const int l = idx & 63;
    const int h = (idx >> 6) & 3;
    const int b = idx >> 8;
    const int lm = landmark[l];
    const int d = threadIdx.x;               // 64 threads = 1 wave

    const float* qrow = q + ((size_t)(b * TT + lm)) * NX + h * HD;
    float qa = qrow[d], qb = qrow[d + 64];
    float sq = qa * qa + qb * qb;
    const float* krow = k + ((size_t)(b * TT + lm)) * NX + h * HD;
    float ka = krow[d], kb = krow[d + 64];
    float sk = ka * ka + kb * kb;
    for (int off = 32; off; off >>= 1) { sq += __shfl_xor(sq, off); sk += __shfl_xor(sk, off); }
    const float invq = rsqrtf(sq) * m1[h * LL + l];   // m1 (4,64,1)
    const float invk = rsqrtf(sk) * m2[h * LL + l];   // m2 (4,1,64)
    float* qo = qn + (((size_t)(b * NH + h)) * LL + l) * HD;
    float* ko = kn + (((size_t)(b * NH + h)) * LL + l) * HD;
    qo[d] = qa * invq;  qo[d + 64] = qb * invq;
    ko[d] = ka * invk;  ko[d + 64] = kb * invk;
}

// w1[b,h,i,l]  = sum_d q[b,i,h*128+d] * kn[b,h,l,d]      (z=0)
// w2t[b,h,j,l] = sum_d k[b,j,h*128+d] * qn[b,h,l,d]      (z=1)
__global__ void k_gemm_w12(const float* __restrict__ q, const float* __restrict__ k,
                           const float* __restrict__ kn, const float* __restrict__ qn,
                           float* __restrict__ w1, float* __restrict__ w2t)
{
    const int m0 = blockIdx.x * 64;          // row tile within T
    const int bh = blockIdx.y;               // b*NH+h, 0..7
    const int h = bh & 3, b = bh >> 2;
    const float* A;
    const float* Bt;
    float* C;
    if (blockIdx.z == 0) {
        A = q + ((size_t)b) * TT * NX + h * HD;
        Bt = kn + ((size_t)bh) * LL * HD;
        C = w1 + ((size_t)bh) * TT * LL;
    } else {
        A = k + ((size_t)b) * TT * NX + h * HD;
        Bt = qn + ((size_t)bh) * LL * HD;
        C = w2t + ((size_t)bh) * TT * LL;
    }
    gemm_tile64(A, NX, Bt, HD, C, LL, HD, m0, 0);
}

// Column sums of V per batch: cs[b, e] = sum_t v[b,t,e]
__global__ void k_colsum(const float* __restrict__ v, float* __restrict__ cs)
{
    const int e = blockIdx.x * 256 + threadIdx.x;   // 0..1023
    const int b = e >> 9, c = e & 511;
    const int t0 = blockIdx.y * 128;
    const float* p = v + ((size_t)b) * TT * NX + c;
    float s = 0.f;
    for (int t = t0; t < t0 + 128; ++t) s += p[(size_t)t * NX];
    atomicAdd(&cs[e], s);
}

// Sparse masked softmax + wmix + PV + RMSNorm, one block per (b, row i).
__global__ void k_sparse_attn(const float* __restrict__ w1, const float* __restrict__ w2t,
                              const float* __restrict__ v, const float* __restrict__ cs,
                              const int* __restrict__ rns, const float* __restrict__ rms_g,
                              const float* __restrict__ scal, float* __restrict__ ao)
{
    const int bi = blockIdx.x;               // b*T + i
    const int b = bi >> 11, i = bi & 2047;
    const int tid = threadIdx.x;             // 256 threads

    __shared__ int cand[32];
    __shared__ int keep[32];
    __shared__ int slist[32];
    __shared__ int scount;
    __shared__ float w1s[3][64];
    __shared__ float plog[3][32];
    __shared__ float wm0[32], wm1[32];
    __shared__ float red[8];

    const int* rrow = rns + ((size_t)bi) * KK;
    if (tid < 32) cand[tid] = rrow[tid];
    __syncthreads();
    if (tid < 32) {
        const int j = cand[tid];
        int dup = 0;
        for (int kk = 0; kk < tid; ++kk) dup |= (cand[kk] == j);   // set-mask: dedupe
        int found = 0;
        const int* jrow = rns + ((size_t)(b * TT + j)) * KK;
        for (int kk = 0; kk < KK; ++kk) found |= (jrow[kk] == i);  // symmetric condition
        keep[tid] = (!dup) && found;
    }
    // stage w1 rows for heads 1..3 (head 0 cancels out of wmix)
    if (tid >= 64) {
        const int t2 = tid - 64;            // 0..191
        const int hh = t2 >> 6, l = t2 & 63;
        w1s[hh][l] = w1[(((size_t)(b * NH + hh + 1)) * TT + i) * LL + l];
    }
    __syncthreads();
    if (tid == 0) {
        int n = 0;
        for (int kk = 0; kk < 32; ++kk) if (keep[kk]) slist[n++] = cand[kk];
        scount = n;
    }
    __syncthreads();
    const int sc = scount;
    const float lam = scal[0], lam_init = scal[1];

    if (sc > 0) {
        if (tid < 96) {                      // logits: 3 heads x up-to-32 targets
            const int hh = tid >> 5, ss = tid & 31;
            if (ss < sc) {
                const int j = slist[ss];
                const float* w2row = w2t + (((size_t)(b * NH + hh + 1)) * TT + j) * LL;
                float acc = 0.f;
                #pragma unroll
                for (int l = 0; l < LL; ++l) acc += w1s[hh][l] * w2row[l];
                plog[hh][ss] = acc;
            }
        }
        __syncthreads();
        if (tid < 3) {                       // per-head softmax over S
            float mx = -1e30f;
            for (int ss = 0; ss < sc; ++ss) mx = fmaxf(mx, plog[tid][ss]);
            float s = 0.f;
            for (int ss = 0; ss < sc; ++ss) { float e = expf(plog[tid][ss] - mx); plog[tid][ss] = e; s += e; }
            const float inv = 1.0f / s;
            for (int ss = 0; ss < sc; ++ss) plog[tid][ss] *= inv;
        }
        __syncthreads();
        if (tid < 32 && tid < sc) {
            const float p1 = plog[0][tid], p2 = plog[1][tid], p3 = plog[2][tid];
            wm0[tid] = (1.0f - lam) * p2 - lam * p1;
            wm1[tid] = p2 - p1 + (1.0f - 2.0f * lam) * p3;
        }
        __syncthreads();
    }

    float acc0 = 0.f, acc1 = 0.f;
    if (sc == 0) {
        // fully-masked row -> softmax uniform over all T -> wmix = (1-2lam)/T everywhere
        const float cc = (1.0f - 2.0f * lam) * (1.0f / (float)TT);
        acc0 = cc * cs[b * NX + tid];
        acc1 = cc * cs[b * NX + 256 + tid];
    } else {
        for (int ss = 0; ss < sc; ++ss) {
            const float* vrow = v + ((size_t)(b * TT + slist[ss])) * NX;
            acc0 += wm0[ss] * vrow[tid];
            acc1 += wm1[ss] * vrow[tid + 256];
        }
    }

    // RMSNorm per 256-half (head 0: e=tid, head 1: e=tid+256)
    float s0 = acc0 * acc0, s1 = acc1 * acc1;
    for (int off = 32; off; off >>= 1) { s0 += __shfl_xor(s0, off); s1 += __shfl_xor(s1, off); }
    const int wave = tid >> 6;
    if ((tid & 63) == 0) { red[wave] = s0; red[4 + wave] = s1; }
    __syncthreads();
    const float t0 = red[0] + red[1] + red[2] + red[3];
    const float t1 = red[4] + red[5] + red[6] + red[7];
    const float sc0 = rsqrtf(t0 * (1.0f / 256.0f) + 1e-5f);
    const float sc1 = rsqrtf(t1 * (1.0f / 256.0f) + 1e-5f);
    const float og = 1.0f - lam_init;
    const float g = rms_g[tid];
    float* aorow = ao + ((size_t)bi) * NX;
    aorow[tid]       = acc0 * sc0 * g * og;
    aorow[tid + 256] = acc1 * sc1 * g * og;
}

extern "C" void kernel_launch(void* const* d_in, const int* in_sizes, int n_in,
                              void* d_out, int out_size, void* d_ws, size_t ws_size,
                              hipStream_t stream)
{
    const float* x    = (const float*)d_in[0];
    const float* wq   = (const float*)d_in[1];
    const float* wk   = (const float*)d_in[2];
    const float* wv   = (const float*)d_in[3];
    const float* wo   = (const float*)d_in[4];
    const float* m1   = (const float*)d_in[5];
    const float* m2   = (const float*)d_in[6];
    const float* lq1  = (const float*)d_in[7];
    const float* lk1  = (const float*)d_in[8];
    const float* lq2  = (const float*)d_in[9];
    const float* lk2  = (const float*)d_in[10];
    const float* rmsg = (const float*)d_in[11];
    const int*   lint = (const int*)d_in[12];
    const int*   rns  = (const int*)d_in[14];
    const int*   lmk  = (const int*)d_in[15];
    float* out = (float*)d_out;
    float* ws  = (float*)d_ws;

    // workspace layout (floats)
    float* q    = ws + 0;          // 2,097,152
    float* k    = ws + 2097152;    // 2,097,152
    float* v    = ws + 4194304;    // 2,097,152
    float* ao   = ws + 6291456;    // 2,097,152
    float* w1   = ws + 8388608;    // 1,048,576
    float* w2t  = ws + 9437184;    // 1,048,576
    float* qn   = ws + 10485760;   // 65,536
    float* kn   = ws + 10551296;   // 65,536
    float* cs   = ws + 10616832;   // 1,024
    float* scal = ws + 10617856;   // 2

    k_prep<<<1, 64, 0, stream>>>(lq1, lk1, lq2, lk2, lint, scal);
    k_gemm_qkv<<<dim3(64, 8, 3), 256, 0, stream>>>(x, wq, wk, wv, q, k, v);
    k_norm_lm<<<512, 64, 0, stream>>>(q, k, m1, m2, lmk, qn, kn);
    k_gemm_w12<<<dim3(32, 8, 2), 256, 0, stream>>>(q, k, kn, qn, w1, w2t);
    hipMemsetAsync(cs, 0, 1024 * sizeof(float), stream);
    k_colsum<<<dim3(4, 16), 256, 0, stream>>>(v, cs);
    k_sparse_attn<<<BB * TT, 256, 0, stream>>>(w1, w2t, v, cs, rns, rmsg, scal, ao);
    k_gemm_out<<<dim3(64, 8, 1), 256, 0, stream>>>(ao, wo, out);
}

// Round 3
// 216.720 us; speedup vs baseline: 1.5306x; 1.5306x over previous
//
#include <hip/hip_runtime.h>
#include <hip/hip_bf16.h>

// Problem constants
#define BB 2
#define TT 2048
#define NX 512
#define NH 4      // 2*H
#define HD 128
#define LL 64
#define KK 32

typedef __bf16 bf16x8 __attribute__((ext_vector_type(8)));
typedef float f32x4 __attribute__((ext_vector_type(4)));
typedef const unsigned int __attribute__((address_space(1)))* gptr_t;
typedef unsigned int __attribute__((address_space(3)))* lptr_t;

__device__ __forceinline__ unsigned short f2bf(float f) {
    unsigned u = __float_as_uint(f);
    unsigned r = (u + 0x7fffu + ((u >> 16) & 1u)) >> 16;   // RNE
    return (unsigned short)r;
}
__device__ __forceinline__ float bf2f(unsigned short h) {
    return __uint_as_float(((unsigned)h) << 16);
}

// ---------------------------------------------------------------------------
// Split f32 -> (hi, lo) bf16.  4 elems/thread.
// ---------------------------------------------------------------------------
__global__ void k_split(const float* __restrict__ src, unsigned short* __restrict__ hi,
                        unsigned short* __restrict__ lo)
{
    const int i = (blockIdx.x * 256 + threadIdx.x) * 4;
    const float4 v = *reinterpret_cast<const float4*>(src + i);
    ushort4 h, l;
    h.x = f2bf(v.x); l.x = f2bf(v.x - bf2f(h.x));
    h.y = f2bf(v.y); l.y = f2bf(v.y - bf2f(h.y));
    h.z = f2bf(v.z); l.z = f2bf(v.z - bf2f(h.z));
    h.w = f2bf(v.w); l.w = f2bf(v.w - bf2f(h.w));
    *reinterpret_cast<ushort4*>(hi + i) = h;
    *reinterpret_cast<ushort4*>(lo + i) = l;
}

// ---------------------------------------------------------------------------
// Split-bf16 MFMA GEMM:  C[m, n] = sum_k A[m,k] * W[n,k]  (near-f32 exact)
// Virtual K' = 1536: segs A = hi,hi,lo ; B = hi,lo,hi  (drops only lo*lo).
// 128x128 tile, BK=32, 4 waves, global_load_lds(16B), mfma_f32_16x16x32_bf16.
// C columns are split across (c0,c1,c2) in 512-wide segments (QKV fusion).
// ---------------------------------------------------------------------------
__global__ __launch_bounds__(256) void k_mfma_split_gemm(
    const unsigned short* __restrict__ a_hi, const unsigned short* __restrict__ a_lo,
    const unsigned short* __restrict__ b_hi, const unsigned short* __restrict__ b_lo,
    float* __restrict__ c0, float* __restrict__ c1, float* __restrict__ c2)
{
    __shared__ unsigned short lsA[128 * 32];
    __shared__ unsigned short lsB[128 * 32];
    const int tid = threadIdx.x;
    const int m0 = blockIdx.x * 128, n0 = blockIdx.y * 128;
    float* cb = (n0 < 512) ? c0 : (n0 < 1024) ? c1 : c2;
    const int ncol0 = n0 & 511;
    const int l = tid & 63;
    const int wr = ((tid >> 6) >> 1) * 64;   // wave row offset in tile
    const int wc = ((tid >> 6) & 1) * 64;    // wave col offset in tile
    const int lr = l & 15, lk8 = (l >> 4) * 8;
    f32x4 acc[4][4] = {};

    const int srow = tid >> 2;               // staging row 0..63
    const int scol = (tid & 3) * 8;          // staging col 0,8,16,24

    for (int kt = 0; kt < 48; ++kt) {
        const int seg = kt >> 4;
        const int koff = (kt & 15) * 32;
        const unsigned short* ab = (seg < 2 ? a_hi : a_lo) + koff + scol;
        const unsigned short* bb = (seg == 1 ? b_lo : b_hi) + koff + scol;
        __builtin_amdgcn_global_load_lds((gptr_t)(ab + (size_t)(m0 + srow) * 512),
                                         (lptr_t)(lsA + tid * 8), 16, 0, 0);
        __builtin_amdgcn_global_load_lds((gptr_t)(ab + (size_t)(m0 + 64 + srow) * 512),
                                         (lptr_t)(lsA + 2048 + tid * 8), 16, 0, 0);
        __builtin_amdgcn_global_load_lds((gptr_t)(bb + (size_t)(n0 + srow) * 512),
                                         (lptr_t)(lsB + tid * 8), 16, 0, 0);
        __builtin_amdgcn_global_load_lds((gptr_t)(bb + (size_t)(n0 + 64 + srow) * 512),
                                         (lptr_t)(lsB + 2048 + tid * 8), 16, 0, 0);
        __syncthreads();   // barrier drains vmcnt -> LDS writes visible
        bf16x8 af[4], bfm[4];
        #pragma unroll
        for (int m = 0; m < 4; ++m)
            af[m] = *reinterpret_cast<const bf16x8*>(&lsA[(wr + m * 16 + lr) * 32 + lk8]);
        #pragma unroll
        for (int n = 0; n < 4; ++n)
            bfm[n] = *reinterpret_cast<const bf16x8*>(&lsB[(wc + n * 16 + lr) * 32 + lk8]);
        #pragma unroll
        for (int m = 0; m < 4; ++m)
            #pragma unroll
            for (int n = 0; n < 4; ++n)
                acc[m][n] = __builtin_amdgcn_mfma_f32_16x16x32_bf16(af[m], bfm[n], acc[m][n], 0, 0, 0);
        __syncthreads();   // LDS reads done before next stage overwrites
    }

    #pragma unroll
    for (int m = 0; m < 4; ++m) {
        const int row = m0 + wr + m * 16 + (l >> 4) * 4;
        #pragma unroll
        for (int n = 0; n < 4; ++n) {
            const int col = ncol0 + wc + n * 16 + lr;
            #pragma unroll
            for (int r = 0; r < 4; ++r)
                cb[(size_t)(row + r) * 512 + col] = acc[m][n][r];
        }
    }
}

// lam / lam_init scalars
__global__ void k_prep(const float* __restrict__ lq1, const float* __restrict__ lk1,
                       const float* __restrict__ lq2, const float* __restrict__ lk2,
                       const int* __restrict__ lint, float* __restrict__ scal)
{
    const int tid = threadIdx.x;  // 64 threads = 1 wave
    float s1 = lq1[tid] * lk1[tid] + lq1[tid + 64] * lk1[tid + 64];
    float s2 = lq2[tid] * lk2[tid] + lq2[tid + 64] * lk2[tid + 64];
    for (int off = 32; off; off >>= 1) { s1 += __shfl_xor(s1, off); s2 += __shfl_xor(s2, off); }
    if (tid == 0) {
        float lam_init = 0.8f - 0.6f * expf(-0.3f * (float)lint[0]);
        float lam = expf(s1) - expf(s2) + lam_init;
        scal[0] = lam;
        scal[1] = lam_init;
    }
}

// Normalized landmark rows, scales folded in.
__global__ void k_norm_lm(const float* __restrict__ q, const float* __restrict__ k,
                          const float* __restrict__ m1, const float* __restrict__ m2,
                          const int* __restrict__ landmark,
                          float* __restrict__ qn, float* __restrict__ kn)
{
    const int idx = blockIdx.x;              // B*NH*L = 512 blocks
    const int l = idx & 63;
    const int h = (idx >> 6) & 3;
    const int b = idx >> 8;
    const int lm = landmark[l];
    const int d = threadIdx.x;               // 64 threads = 1 wave

    const float* qrow = q + ((size_t)(b * TT + lm)) * NX + h * HD;
    float qa = qrow[d], qb = qrow[d + 64];
    float sq = qa * qa + qb * qb;
    const float* krow = k + ((size_t)(b * TT + lm)) * NX + h * HD;
    float ka = krow[d], kb = krow[d + 64];
    float sk = ka * ka + kb * kb;
    for (int off = 32; off; off >>= 1) { sq += __shfl_xor(sq, off); sk += __shfl_xor(sk, off); }
    const float invq = rsqrtf(sq) * m1[h * LL + l];
    const float invk = rsqrtf(sk) * m2[h * LL + l];
    float* qo = qn + (((size_t)(b * NH + h)) * LL + l) * HD;
    float* ko = kn + (((size_t)(b * NH + h)) * LL + l) * HD;
    qo[d] = qa * invq;  qo[d + 64] = qb * invq;
    ko[d] = ka * invk;  ko[d + 64] = kb * invk;
}

// f32 64x64 GEMM tile used for the small w1/w2 GEMMs (K=128 only).
__device__ __forceinline__ void gemm_tile64(const float* __restrict__ A, int lda,
                                            const float* __restrict__ Bw, int ldb,
                                            float* __restrict__ C, int ldc,
                                            int Kdim, int m0, int n0)
{
    __shared__ float As[64][17];
    __shared__ float Bs[64][17];
    const int tid = threadIdx.x;
    const int tx = tid & 15, ty = tid >> 4;
    float acc[4][4] = {};

    for (int k0 = 0; k0 < Kdim; k0 += 16) {
        const int flat = tid * 4;
        const int r = flat >> 4, c = flat & 15;
        const float4 av = *reinterpret_cast<const float4*>(&A[(size_t)(m0 + r) * lda + k0 + c]);
        const float4 bv = *reinterpret_cast<const float4*>(&Bw[(size_t)(n0 + r) * ldb + k0 + c]);
        __syncthreads();
        As[r][c] = av.x; As[r][c + 1] = av.y; As[r][c + 2] = av.z; As[r][c + 3] = av.w;
        Bs[r][c] = bv.x; Bs[r][c + 1] = bv.y; Bs[r][c + 2] = bv.z; Bs[r][c + 3] = bv.w;
        __syncthreads();
        #pragma unroll
        for (int kk = 0; kk < 16; ++kk) {
            float a0 = As[ty * 4 + 0][kk], a1 = As[ty * 4 + 1][kk];
            float a2 = As[ty * 4 + 2][kk], a3 = As[ty * 4 + 3][kk];
            float b0 = Bs[tx * 4 + 0][kk], b1 = Bs[tx * 4 + 1][kk];
            float b2 = Bs[tx * 4 + 2][kk], b3 = Bs[tx * 4 + 3][kk];
            acc[0][0] += a0 * b0; acc[0][1] += a0 * b1; acc[0][2] += a0 * b2; acc[0][3] += a0 * b3;
            acc[1][0] += a1 * b0; acc[1][1] += a1 * b1; acc[1][2] += a1 * b2; acc[1][3] += a1 * b3;
            acc[2][0] += a2 * b0; acc[2][1] += a2 * b1; acc[2][2] += a2 * b2; acc[2][3] += a2 * b3;
            acc[3][0] += a3 * b0; acc[3][1] += a3 * b1; acc[3][2] += a3 * b2; acc[3][3] += a3 * b3;
        }
    }
    #pragma unroll
    for (int i = 0; i < 4; ++i)
        #pragma unroll
        for (int j = 0; j < 4; ++j)
            C[(size_t)(m0 + ty * 4 + i) * ldc + n0 + tx * 4 + j] = acc[i][j];
}

// w1[b,h,i,l]  = sum_d q[b,i,h*128+d] * kn[b,h,l,d]      (z=0)
// w2t[b,h,j,l] = sum_d k[b,j,h*128+d] * qn[b,h,l,d]      (z=1)
__global__ void k_gemm_w12(const float* __restrict__ q, const float* __restrict__ k,
                           const float* __restrict__ kn, const float* __restrict__ qn,
                           float* __restrict__ w1, float* __restrict__ w2t)
{
    const int m0 = blockIdx.x * 64;
    const int bh = blockIdx.y;
    const int h = bh & 3, b = bh >> 2;
    const float* A;
    const float* Bt;
    float* C;
    if (blockIdx.z == 0) {
        A = q + ((size_t)b) * TT * NX + h * HD;
        Bt = kn + ((size_t)bh) * LL * HD;
        C = w1 + ((size_t)bh) * TT * LL;
    } else {
        A = k + ((size_t)b) * TT * NX + h * HD;
        Bt = qn + ((size_t)bh) * LL * HD;
        C = w2t + ((size_t)bh) * TT * LL;
    }
    gemm_tile64(A, NX, Bt, HD, C, LL, HD, m0, 0);
}

// Column sums of V per batch: cs[b, e] = sum_t v[b,t,e]
__global__ void k_colsum(const float* __restrict__ v, float* __restrict__ cs)
{
    const int e = blockIdx.x * 256 + threadIdx.x;   // 0..1023
    const int b = e >> 9, c = e & 511;
    const int t0 = blockIdx.y * 128;
    const float* p = v + ((size_t)b) * TT * NX + c;
    float s = 0.f;
    for (int t = t0; t < t0 + 128; ++t) s += p[(size_t)t * NX];
    atomicAdd(&cs[e], s);
}

// Sparse masked softmax + wmix + PV + RMSNorm; emits ao as (hi,lo) bf16 split.
__global__ void k_sparse_attn(const float* __restrict__ w1, const float* __restrict__ w2t,
                              const float* __restrict__ v, const float* __restrict__ cs,
                              const int* __restrict__ rns, const float* __restrict__ rms_g,
                              const float* __restrict__ scal,
                              unsigned short* __restrict__ ao_hi,
                              unsigned short* __restrict__ ao_lo)
{
    const int bi = blockIdx.x;               // b*T + i
    const int b = bi >> 11, i = bi & 2047;
    const int tid = threadIdx.x;             // 256 threads

    __shared__ int cand[32];
    __shared__ int keep[32];
    __shared__ int slist[32];
    __shared__ int scount;
    __shared__ float w1s[3][64];
    __shared__ float plog[3][32];
    __shared__ float wm0[32], wm1[32];
    __shared__ float red[8];

    const int* rrow = rns + ((size_t)bi) * KK;
    if (tid < 32) cand[tid] = rrow[tid];
    __syncthreads();
    if (tid < 32) {
        const int j = cand[tid];
        int dup = 0;
        for (int kk = 0; kk < tid; ++kk) dup |= (cand[kk] == j);
        int found = 0;
        const int* jrow = rns + ((size_t)(b * TT + j)) * KK;
        for (int kk = 0; kk < KK; ++kk) found |= (jrow[kk] == i);
        keep[tid] = (!dup) && found;
    }
    if (tid >= 64) {
        const int t2 = tid - 64;            // heads 1..3 of w1 row i
        const int hh = t2 >> 6, l = t2 & 63;
        w1s[hh][l] = w1[(((size_t)(b * NH + hh + 1)) * TT + i) * LL + l];
    }
    __syncthreads();
    if (tid == 0) {
        int n = 0;
        for (int kk = 0; kk < 32; ++kk) if (keep[kk]) slist[n++] = cand[kk];
        scount = n;
    }
    __syncthreads();
    const int sc = scount;
    const float lam = scal[0], lam_init = scal[1];

    if (sc > 0) {
        if (tid < 96) {
            const int hh = tid >> 5, ss = tid & 31;
            if (ss < sc) {
                const int j = slist[ss];
                const float* w2row = w2t + (((size_t)(b * NH + hh + 1)) * TT + j) * LL;
                float acc = 0.f;
                #pragma unroll
                for (int l = 0; l < LL; ++l) acc += w1s[hh][l] * w2row[l];
                plog[hh][ss] = acc;
            }
        }
        __syncthreads();
        if (tid < 3) {
            float mx = -1e30f;
            for (int ss = 0; ss < sc; ++ss) mx = fmaxf(mx, plog[tid][ss]);
            float s = 0.f;
            for (int ss = 0; ss < sc; ++ss) { float e = expf(plog[tid][ss] - mx); plog[tid][ss] = e; s += e; }
            const float inv = 1.0f / s;
            for (int ss = 0; ss < sc; ++ss) plog[tid][ss] *= inv;
        }
        __syncthreads();
        if (tid < 32 && tid < sc) {
            const float p1 = plog[0][tid], p2 = plog[1][tid], p3 = plog[2][tid];
            wm0[tid] = (1.0f - lam) * p2 - lam * p1;
            wm1[tid] = p2 - p1 + (1.0f - 2.0f * lam) * p3;
        }
        __syncthreads();
    }

    float acc0 = 0.f, acc1 = 0.f;
    if (sc == 0) {
        const float cc = (1.0f - 2.0f * lam) * (1.0f / (float)TT);
        acc0 = cc * cs[b * NX + tid];
        acc1 = cc * cs[b * NX + 256 + tid];
    } else {
        for (int ss = 0; ss < sc; ++ss) {
            const float* vrow = v + ((size_t)(b * TT + slist[ss])) * NX;
            acc0 += wm0[ss] * vrow[tid];
            acc1 += wm1[ss] * vrow[tid + 256];
        }
    }

    float s0 = acc0 * acc0, s1 = acc1 * acc1;
    for (int off = 32; off; off >>= 1) { s0 += __shfl_xor(s0, off); s1 += __shfl_xor(s1, off); }
    const int wave = tid >> 6;
    if ((tid & 63) == 0) { red[wave] = s0; red[4 + wave] = s1; }
    __syncthreads();
    const float t0 = red[0] + red[1] + red[2] + red[3];
    const float t1 = red[4] + red[5] + red[6] + red[7];
    const float sc0 = rsqrtf(t0 * (1.0f / 256.0f) + 1e-5f);
    const float sc1 = rsqrtf(t1 * (1.0f / 256.0f) + 1e-5f);
    const float og = 1.0f - lam_init;
    // rms_g (256,) broadcasts over the LAST axis (e in [0,256)) of a(..,256);
    // flat col = h*256 + e  ->  BOTH halves use rms_g[tid]  (round-2 bug was [tid+256] OOB)
    const float g = rms_g[tid];
    const float v0 = acc0 * sc0 * g * og;
    const float v1 = acc1 * sc1 * g * og;
    unsigned short* hrow = ao_hi + ((size_t)bi) * NX;
    unsigned short* lrow = ao_lo + ((size_t)bi) * NX;
    unsigned short h0 = f2bf(v0), h1 = f2bf(v1);
    hrow[tid] = h0;        lrow[tid] = f2bf(v0 - bf2f(h0));
    hrow[tid + 256] = h1;  lrow[tid + 256] = f2bf(v1 - bf2f(h1));
}

extern "C" void kernel_launch(void* const* d_in, const int* in_sizes, int n_in,
                              void* d_out, int out_size, void* d_ws, size_t ws_size,
                              hipStream_t stream)
{
    const float* x    = (const float*)d_in[0];
    const float* wq   = (const float*)d_in[1];
    const float* wk   = (const float*)d_in[2];
    const float* wv   = (const float*)d_in[3];
    const float* wo   = (const float*)d_in[4];
    const float* m1   = (const float*)d_in[5];
    const float* m2   = (const float*)d_in[6];
    const float* lq1  = (const float*)d_in[7];
    const float* lk1  = (const float*)d_in[8];
    const float* lq2  = (const float*)d_in[9];
    const float* lk2  = (const float*)d_in[10];
    const float* rmsg = (const float*)d_in[11];
    const int*   lint = (const int*)d_in[12];
    const int*   rns  = (const int*)d_in[14];
    const int*   lmk  = (const int*)d_in[15];
    float* out = (float*)d_out;
    float* ws  = (float*)d_ws;

    // workspace layout (float slots)
    float* q    = ws + 0;         // 2,097,152
    float* k    = ws + 2097152;   // 2,097,152
    float* v    = ws + 4194304;   // 2,097,152
    float* w1   = ws + 6291456;   // 1,048,576  (wqkv bf16 splits aliased here pre-w12)
    float* w2t  = ws + 7340032;   // 1,048,576
    float* qn   = ws + 8388608;   // 65,536
    float* kn   = ws + 8454144;   // 65,536
    float* cs   = ws + 8519680;   // 1,024
    float* scal = ws + 8520704;   // 2 (padded to 128)
    unsigned short* xs    = (unsigned short*)(ws + 8520832);  // x_hi/x_lo, 2x 2,097,152 bf16
    unsigned short* x_hi  = xs;
    unsigned short* x_lo  = xs + 2097152;
    unsigned short* ao_hi = x_hi;            // reuse after QKV GEMM consumed x split
    unsigned short* ao_lo = x_lo;
    // wq/wk/wv splits live only until the QKV GEMM; alias into w1's region
    // (w1 is written later by k_gemm_w12 -- stream-ordered, safe).
    unsigned short* wqkv_hi = (unsigned short*)w1;            // 3x 262,144 bf16
    unsigned short* wqkv_lo = wqkv_hi + 3 * 262144;           // 3x 262,144 bf16
    // wo split must survive to the end: own region
    unsigned short* wo_hi = (unsigned short*)(ws + 10617984); // 262,144 bf16
    unsigned short* wo_lo = wo_hi + 262144;                   // 262,144 bf16

    k_prep<<<1, 64, 0, stream>>>(lq1, lk1, lq2, lk2, lint, scal);
    k_split<<<2048, 256, 0, stream>>>(x, x_hi, x_lo);
    k_split<<<256, 256, 0, stream>>>(wq, wqkv_hi + 0 * 262144, wqkv_lo + 0 * 262144);
    k_split<<<256, 256, 0, stream>>>(wk, wqkv_hi + 1 * 262144, wqkv_lo + 1 * 262144);
    k_split<<<256, 256, 0, stream>>>(wv, wqkv_hi + 2 * 262144, wqkv_lo + 2 * 262144);
    k_split<<<256, 256, 0, stream>>>(wo, wo_hi, wo_lo);

    // QKV fused: M=4096, N=1536 (q|k|v), K'=3*512
    k_mfma_split_gemm<<<dim3(32, 12), 256, 0, stream>>>(x_hi, x_lo, wqkv_hi, wqkv_lo, q, k, v);

    k_norm_lm<<<512, 64, 0, stream>>>(q, k, m1, m2, lmk, qn, kn);
    k_gemm_w12<<<dim3(32, 8, 2), 256, 0, stream>>>(q, k, kn, qn, w1, w2t);
    hipMemsetAsync(cs, 0, 1024 * sizeof(float), stream);
    k_colsum<<<dim3(4, 16), 256, 0, stream>>>(v, cs);
    k_sparse_attn<<<BB * TT, 256, 0, stream>>>(w1, w2t, v, cs, rns, rmsg, scal, ao_hi, ao_lo);

    // out = ao @ wo^T: M=4096, N=512, K'=3*512
    k_mfma_split_gemm<<<dim3(32, 4), 256, 0, stream>>>(ao_hi, ao_lo, wo_hi, wo_lo,
                                                       out, out, out);
}

// Round 4
// 177.124 us; speedup vs baseline: 1.8727x; 1.2235x over previous
//
#include <hip/hip_runtime.h>
#include <hip/hip_bf16.h>

// Problem constants
#define BB 2
#define TT 2048
#define NX 512
#define NH 4      // 2*H
#define HD 128
#define LL 64
#define KK 32

typedef __bf16 bf16x8 __attribute__((ext_vector_type(8)));
typedef float f32x4 __attribute__((ext_vector_type(4)));
typedef unsigned short us;
typedef const unsigned int __attribute__((address_space(1)))* gptr_t;
typedef unsigned int __attribute__((address_space(3)))* lptr_t;

__device__ __forceinline__ us f2bf(float f) {
    unsigned u = __float_as_uint(f);
    unsigned r = (u + 0x7fffu + ((u >> 16) & 1u)) >> 16;   // RNE
    return (us)r;
}
__device__ __forceinline__ float bf2f(us h) {
    return __uint_as_float(((unsigned)h) << 16);
}

// ---------------------------------------------------------------------------
// Fused split f32 -> (hi, lo) bf16 for x, wq, wk, wv, wo in one launch.
// Grid: 2048 (x) + 4*256 (weights) = 3072 blocks, 1024 elems/block.
// ---------------------------------------------------------------------------
__global__ void k_split_all(const float* __restrict__ x,
                            const float* __restrict__ wq, const float* __restrict__ wk,
                            const float* __restrict__ wv, const float* __restrict__ wo,
                            us* __restrict__ x_hi, us* __restrict__ x_lo,
                            us* __restrict__ wqkv_hi, us* __restrict__ wqkv_lo,
                            us* __restrict__ wo_hi, us* __restrict__ wo_lo)
{
    const int bidx = blockIdx.x;
    const float* src;
    us* hi;
    us* lo;
    int pos;
    if (bidx < 2048) {
        src = x; hi = x_hi; lo = x_lo;
        pos = bidx * 1024 + threadIdx.x * 4;
    } else {
        const int w = (bidx - 2048) >> 8;          // 0..3
        const int p = (bidx - 2048) & 255;
        pos = p * 1024 + threadIdx.x * 4;
        if (w == 0)      { src = wq; hi = wqkv_hi;          lo = wqkv_lo; }
        else if (w == 1) { src = wk; hi = wqkv_hi + 262144; lo = wqkv_lo + 262144; }
        else if (w == 2) { src = wv; hi = wqkv_hi + 524288; lo = wqkv_lo + 524288; }
        else             { src = wo; hi = wo_hi;            lo = wo_lo; }
    }
    const float4 v = *reinterpret_cast<const float4*>(src + pos);
    ushort4 h, l;
    h.x = f2bf(v.x); l.x = f2bf(v.x - bf2f(h.x));
    h.y = f2bf(v.y); l.y = f2bf(v.y - bf2f(h.y));
    h.z = f2bf(v.z); l.z = f2bf(v.z - bf2f(h.z));
    h.w = f2bf(v.w); l.w = f2bf(v.w - bf2f(h.w));
    *reinterpret_cast<ushort4*>(hi + pos) = h;
    *reinterpret_cast<ushort4*>(lo + pos) = l;
}

// ---------------------------------------------------------------------------
// Split-bf16 MFMA GEMM, BM=64, BN template (128 or 64).
// C[m,n] = sum_k A[m,k]*W[n,k]; K'=1536 (segs: hi.hi, hi.lo, lo.hi).
// 4 waves in 2x2; wave tile 32 x (BN/2). QKV mode (WSPLIT): C cols split
// across c0/c1/c2 per 512-wide segment; q/k regions also emit bf16 splits.
// ---------------------------------------------------------------------------
template<int BN, bool WSPLIT>
__global__ __launch_bounds__(256) void k_gemm_big(
    const us* __restrict__ a_hi, const us* __restrict__ a_lo,
    const us* __restrict__ b_hi, const us* __restrict__ b_lo,
    float* __restrict__ c0, float* __restrict__ c1, float* __restrict__ c2,
    us* __restrict__ qs_hi, us* __restrict__ qs_lo,
    us* __restrict__ ks_hi, us* __restrict__ ks_lo)
{
    constexpr int WC = BN / 2;     // wave col span
    constexpr int NB = WC / 16;    // 4 (BN=128) or 2 (BN=64)
    __shared__ us lsA[64 * 32];
    __shared__ us lsB[BN * 32];
    const int tid = threadIdx.x;
    const int m0 = blockIdx.x * 64, n0 = blockIdx.y * BN;
    const int region = n0 >> 9;                 // 0:q 1:k 2:v
    float* cb = (region == 0) ? c0 : (region == 1) ? c1 : c2;
    const int ncol0 = n0 & 511;
    const int l = tid & 63, wid = tid >> 6;
    const int wr = (wid >> 1) * 32, wc = (wid & 1) * WC;
    const int lr = l & 15, lk8 = (l >> 4) * 8;
    f32x4 acc[2][NB] = {};
    const int srow = tid >> 2;                  // 0..63
    const int scol = (tid & 3) * 8;             // 0,8,16,24

    for (int kt = 0; kt < 48; ++kt) {
        const int seg = kt >> 4;
        const int koff = (kt & 15) * 32;
        const us* ab = (seg < 2 ? a_hi : a_lo) + koff + scol;
        const us* bb = (seg == 1 ? b_lo : b_hi) + koff + scol;
        __builtin_amdgcn_global_load_lds((gptr_t)(ab + (size_t)(m0 + srow) * 512),
                                         (lptr_t)(lsA + tid * 8), 16, 0, 0);
        __builtin_amdgcn_global_load_lds((gptr_t)(bb + (size_t)(n0 + srow) * 512),
                                         (lptr_t)(lsB + tid * 8), 16, 0, 0);
        if constexpr (BN == 128) {
            __builtin_amdgcn_global_load_lds((gptr_t)(bb + (size_t)(n0 + 64 + srow) * 512),
                                             (lptr_t)(lsB + 2048 + tid * 8), 16, 0, 0);
        }
        __syncthreads();   // barrier drains vmcnt -> LDS writes visible
        bf16x8 af[2], bfr[NB];
        #pragma unroll
        for (int m = 0; m < 2; ++m)
            af[m] = *reinterpret_cast<const bf16x8*>(&lsA[(wr + m * 16 + lr) * 32 + lk8]);
        #pragma unroll
        for (int n = 0; n < NB; ++n)
            bfr[n] = *reinterpret_cast<const bf16x8*>(&lsB[(wc + n * 16 + lr) * 32 + lk8]);
        #pragma unroll
        for (int m = 0; m < 2; ++m)
            #pragma unroll
            for (int n = 0; n < NB; ++n)
                acc[m][n] = __builtin_amdgcn_mfma_f32_16x16x32_bf16(af[m], bfr[n], acc[m][n], 0, 0, 0);
        __syncthreads();
    }

    us* sh = (region == 0) ? qs_hi : ks_hi;
    us* slo = (region == 0) ? qs_lo : ks_lo;
    #pragma unroll
    for (int m = 0; m < 2; ++m) {
        const int row = m0 + wr + m * 16 + (l >> 4) * 4;
        #pragma unroll
        for (int n = 0; n < NB; ++n) {
            const int col = ncol0 + wc + n * 16 + lr;
            #pragma unroll
            for (int r = 0; r < 4; ++r) {
                const float val = acc[m][n][r];
                cb[(size_t)(row + r) * 512 + col] = val;
                if constexpr (WSPLIT) {
                    if (region < 2) {
                        const us h = f2bf(val);
                        sh[(size_t)(row + r) * 512 + col] = h;
                        slo[(size_t)(row + r) * 512 + col] = f2bf(val - bf2f(h));
                    }
                }
            }
        }
    }
}

// ---------------------------------------------------------------------------
// w12 split-bf16 MFMA: BM=64, BN=64, K=128 (K'=384, 12 k-steps).
// z=0: w1[bh,i,l] = q[b,i,h*128+:] . kn[bh,l,:]
// z=1: w2t[bh,j,l] = k[b,j,h*128+:] . qn[bh,l,:]
// ---------------------------------------------------------------------------
__global__ __launch_bounds__(256) void k_gemm_w12(
    const us* __restrict__ q_hi, const us* __restrict__ q_lo,
    const us* __restrict__ k_hi, const us* __restrict__ k_lo,
    const us* __restrict__ kn_hi, const us* __restrict__ kn_lo,
    const us* __restrict__ qn_hi, const us* __restrict__ qn_lo,
    float* __restrict__ w1, float* __restrict__ w2t)
{
    __shared__ us lsA[64 * 32];
    __shared__ us lsB[64 * 32];
    const int tid = threadIdx.x;
    const int m0 = blockIdx.x * 64;
    const int bh = blockIdx.y;                   // b*4+h
    const int h = bh & 3, b = bh >> 2;
    const int z = blockIdx.z;
    const us* ah = (z ? k_hi : q_hi) + ((size_t)b * 2048) * 512 + h * 128;
    const us* al = (z ? k_lo : q_lo) + ((size_t)b * 2048) * 512 + h * 128;
    const us* bh_p = (z ? qn_hi : kn_hi) + (size_t)bh * 64 * 128;
    const us* bl_p = (z ? qn_lo : kn_lo) + (size_t)bh * 64 * 128;
    float* C = (z ? w2t : w1) + (size_t)bh * 2048 * 64;

    const int l = tid & 63, wid = tid >> 6;
    const int wr = (wid >> 1) * 32, wc = (wid & 1) * 32;
    const int lr = l & 15, lk8 = (l >> 4) * 8;
    f32x4 acc[2][2] = {};
    const int srow = tid >> 2, scol = (tid & 3) * 8;

    for (int kt = 0; kt < 12; ++kt) {
        const int seg = kt >> 2;
        const int koff = (kt & 3) * 32;
        const us* ab = (seg < 2 ? ah : al) + koff + scol;
        const us* bb = (seg == 1 ? bl_p : bh_p) + koff + scol;
        __builtin_amdgcn_global_load_lds((gptr_t)(ab + (size_t)(m0 + srow) * 512),
                                         (lptr_t)(lsA + tid * 8), 16, 0, 0);
        __builtin_amdgcn_global_load_lds((gptr_t)(bb + (size_t)srow * 128),
                                         (lptr_t)(lsB + tid * 8), 16, 0, 0);
        __syncthreads();
        bf16x8 af[2], bfr[2];
        #pragma unroll
        for (int m = 0; m < 2; ++m)
            af[m] = *reinterpret_cast<const bf16x8*>(&lsA[(wr + m * 16 + lr) * 32 + lk8]);
        #pragma unroll
        for (int n = 0; n < 2; ++n)
            bfr[n] = *reinterpret_cast<const bf16x8*>(&lsB[(wc + n * 16 + lr) * 32 + lk8]);
        #pragma unroll
        for (int m = 0; m < 2; ++m)
            #pragma unroll
            for (int n = 0; n < 2; ++n)
                acc[m][n] = __builtin_amdgcn_mfma_f32_16x16x32_bf16(af[m], bfr[n], acc[m][n], 0, 0, 0);
        __syncthreads();
    }

    #pragma unroll
    for (int m = 0; m < 2; ++m) {
        const int row = m0 + wr + m * 16 + (l >> 4) * 4;
        #pragma unroll
        for (int n = 0; n < 2; ++n) {
            const int col = wc + n * 16 + lr;
            #pragma unroll
            for (int r = 0; r < 4; ++r)
                C[(size_t)(row + r) * 64 + col] = acc[m][n][r];
        }
    }
}

// lam / lam_init scalars
__global__ void k_prep(const float* __restrict__ lq1, const float* __restrict__ lk1,
                       const float* __restrict__ lq2, const float* __restrict__ lk2,
                       const int* __restrict__ lint, float* __restrict__ scal)
{
    const int tid = threadIdx.x;  // 64 threads = 1 wave
    float s1 = lq1[tid] * lk1[tid] + lq1[tid + 64] * lk1[tid + 64];
    float s2 = lq2[tid] * lk2[tid] + lq2[tid + 64] * lk2[tid + 64];
    for (int off = 32; off; off >>= 1) { s1 += __shfl_xor(s1, off); s2 += __shfl_xor(s2, off); }
    if (tid == 0) {
        float lam_init = 0.8f - 0.6f * expf(-0.3f * (float)lint[0]);
        float lam = expf(s1) - expf(s2) + lam_init;
        scal[0] = lam;
        scal[1] = lam_init;
    }
}

// Normalized landmark rows -> bf16 hi/lo splits, scales folded in.
__global__ void k_norm_lm(const float* __restrict__ q, const float* __restrict__ k,
                          const float* __restrict__ m1, const float* __restrict__ m2,
                          const int* __restrict__ landmark,
                          us* __restrict__ qn_hi, us* __restrict__ qn_lo,
                          us* __restrict__ kn_hi, us* __restrict__ kn_lo)
{
    const int idx = blockIdx.x;              // B*NH*L = 512 blocks
    const int l = idx & 63;
    const int h = (idx >> 6) & 3;
    const int b = idx >> 8;
    const int lm = landmark[l];
    const int d = threadIdx.x;               // 64 threads = 1 wave

    const float* qrow = q + ((size_t)(b * TT + lm)) * NX + h * HD;
    float qa = qrow[d], qb = qrow[d + 64];
    float sq = qa * qa + qb * qb;
    const float* krow = k + ((size_t)(b * TT + lm)) * NX + h * HD;
    float ka = krow[d], kb = krow[d + 64];
    float sk = ka * ka + kb * kb;
    for (int off = 32; off; off >>= 1) { sq += __shfl_xor(sq, off); sk += __shfl_xor(sk, off); }
    const float invq = rsqrtf(sq) * m1[h * LL + l];
    const float invk = rsqrtf(sk) * m2[h * LL + l];
    const size_t base = (((size_t)(b * NH + h)) * LL + l) * HD;
    const float vq0 = qa * invq, vq1 = qb * invq;
    const float vk0 = ka * invk, vk1 = kb * invk;
    us h0;
    h0 = f2bf(vq0); qn_hi[base + d] = h0;      qn_lo[base + d] = f2bf(vq0 - bf2f(h0));
    h0 = f2bf(vq1); qn_hi[base + d + 64] = h0; qn_lo[base + d + 64] = f2bf(vq1 - bf2f(h0));
    h0 = f2bf(vk0); kn_hi[base + d] = h0;      kn_lo[base + d] = f2bf(vk0 - bf2f(h0));
    h0 = f2bf(vk1); kn_hi[base + d + 64] = h0; kn_lo[base + d + 64] = f2bf(vk1 - bf2f(h0));
}

// Column sums of V per batch: cs[b, e] = sum_t v[b,t,e]
__global__ void k_colsum(const float* __restrict__ v, float* __restrict__ cs)
{
    const int e = blockIdx.x * 256 + threadIdx.x;   // 0..1023
    const int b = e >> 9, c = e & 511;
    const int t0 = blockIdx.y * 128;
    const float* p = v + ((size_t)b) * TT * NX + c;
    float s = 0.f;
    for (int t = t0; t < t0 + 128; ++t) s += p[(size_t)t * NX];
    atomicAdd(&cs[e], s);
}

// ---------------------------------------------------------------------------
// Sparse masked softmax + wmix + PV + RMSNorm. ONE WAVE per (b, row i);
// wave-synchronous (no __syncthreads). 4 independent waves per block.
// ---------------------------------------------------------------------------
__global__ __launch_bounds__(256) void k_sparse_attn(
    const float* __restrict__ w1, const float* __restrict__ w2t,
    const float* __restrict__ v, const float* __restrict__ cs,
    const int* __restrict__ rns, const float* __restrict__ rms_g,
    const float* __restrict__ scal,
    us* __restrict__ ao_hi, us* __restrict__ ao_lo)
{
    const int wid = threadIdx.x >> 6;
    const int lane = threadIdx.x & 63;
    const int bi = blockIdx.x * 4 + wid;     // 0..4095
    const int b = bi >> 11, i = bi & 2047;

    __shared__ int   sl[4][32];
    __shared__ float plog[4][96];
    __shared__ float wmm[4][2][32];
    __shared__ float w1s[4][3][64];

    // stage w1 rows (heads 1..3) for row i: 192 floats by 64 lanes
    #pragma unroll
    for (int r = 0; r < 3; ++r) {
        const int t = r * 64 + lane;
        const int hh = t >> 6, l2 = t & 63;
        w1s[wid][hh][l2] = w1[(((size_t)(b * NH + hh + 1)) * TT + i) * LL + l2];
    }

    // candidates + dedup + symmetric check
    const int myidx = lane & 31;
    const int cand = rns[(size_t)bi * KK + myidx];
    int dup = 0;
    #pragma unroll
    for (int kk = 0; kk < 31; ++kk) {
        const int other = __shfl(cand, kk);
        dup |= (kk < myidx) & (other == cand);
    }
    const int* jrow = rns + ((size_t)(b * TT + cand)) * KK + (lane >> 5) * 16;
    int found = 0;
    #pragma unroll
    for (int kk = 0; kk < 16; ++kk) found |= (jrow[kk] == i);
    found |= __shfl_xor(found, 32);
    const int keep = (!dup) && found;
    const unsigned long long mask = __ballot(keep) & 0xffffffffull;
    const int sc = __popcll(mask);
    const int pos = __popcll(mask & ((1ull << myidx) - 1ull));
    if (lane < 32 && keep) sl[wid][pos] = cand;

    const float lam = scal[0], lam_init = scal[1];

    if (sc > 0) {
        // logits: tasks t = ss*3 + hh, 8 lanes per task
        const int ntask = 3 * sc;
        for (int t0 = 0; t0 < ntask; t0 += 8) {
            const int t = t0 + (lane >> 3);
            float part = 0.f;
            if (t < ntask) {
                const int hh = t % 3, ss = t / 3;
                const int j = sl[wid][ss];
                const float* w2row = w2t + (((size_t)(b * NH + hh + 1)) * TT + j) * LL + (lane & 7) * 8;
                const float* w1p = &w1s[wid][hh][(lane & 7) * 8];
                #pragma unroll
                for (int e = 0; e < 8; ++e) part += w1p[e] * w2row[e];
            }
            part += __shfl_xor(part, 1);
            part += __shfl_xor(part, 2);
            part += __shfl_xor(part, 4);
            if (t < ntask && (lane & 7) == 0) plog[wid][t] = part;
        }
        // per-head softmax over sc entries (3 lanes, sc typically 1-3)
        if (lane < 3) {
            float mx = -1e30f;
            for (int ss = 0; ss < sc; ++ss) mx = fmaxf(mx, plog[wid][ss * 3 + lane]);
            float s = 0.f;
            for (int ss = 0; ss < sc; ++ss) {
                const float e = expf(plog[wid][ss * 3 + lane] - mx);
                plog[wid][ss * 3 + lane] = e;
                s += e;
            }
            const float inv = 1.0f / s;
            for (int ss = 0; ss < sc; ++ss) plog[wid][ss * 3 + lane] *= inv;
        }
        if (lane < sc) {
            const float p1 = plog[wid][lane * 3 + 0];
            const float p2 = plog[wid][lane * 3 + 1];
            const float p3 = plog[wid][lane * 3 + 2];
            wmm[wid][0][lane] = (1.0f - lam) * p2 - lam * p1;
            wmm[wid][1][lane] = p2 - p1 + (1.0f - 2.0f * lam) * p3;
        }
    }

    // PV: each lane owns cols [lane*4, lane*4+4) of both 256-halves
    f32x4 acc0 = {0.f, 0.f, 0.f, 0.f}, acc1 = {0.f, 0.f, 0.f, 0.f};
    if (sc == 0) {
        const float cc = (1.0f - 2.0f * lam) * (1.0f / (float)TT);
        const f32x4 c0 = *reinterpret_cast<const f32x4*>(cs + b * NX + lane * 4);
        const f32x4 c1 = *reinterpret_cast<const f32x4*>(cs + b * NX + 256 + lane * 4);
        acc0 = cc * c0;
        acc1 = cc * c1;
    } else {
        for (int ss = 0; ss < sc; ++ss) {
            const float wa = wmm[wid][0][ss], wb = wmm[wid][1][ss];
            const float* vrow = v + ((size_t)(b * TT + sl[wid][ss])) * NX;
            const f32x4 va = *reinterpret_cast<const f32x4*>(vrow + lane * 4);
            const f32x4 vb = *reinterpret_cast<const f32x4*>(vrow + 256 + lane * 4);
            acc0 += wa * va;
            acc1 += wb * vb;
        }
    }

    // RMSNorm per half
    float s0 = acc0[0]*acc0[0] + acc0[1]*acc0[1] + acc0[2]*acc0[2] + acc0[3]*acc0[3];
    float s1 = acc1[0]*acc1[0] + acc1[1]*acc1[1] + acc1[2]*acc1[2] + acc1[3]*acc1[3];
    #pragma unroll
    for (int off = 32; off; off >>= 1) { s0 += __shfl_xor(s0, off); s1 += __shfl_xor(s1, off); }
    const float sc0 = rsqrtf(s0 * (1.0f / 256.0f) + 1e-5f);
    const float sc1 = rsqrtf(s1 * (1.0f / 256.0f) + 1e-5f);
    const float og = 1.0f - lam_init;
    // rms_g (256,) broadcasts over the last axis: BOTH halves use rms_g[e]
    const f32x4 g = *reinterpret_cast<const f32x4*>(rms_g + lane * 4);
    ushort4 h0, l0, h1, l1;
    #pragma unroll
    for (int e = 0; e < 4; ++e) {
        const float v0 = acc0[e] * sc0 * g[e] * og;
        const float v1 = acc1[e] * sc1 * g[e] * og;
        const us a = f2bf(v0);
        const us bq = f2bf(v1);
        (&h0.x)[e] = a;  (&l0.x)[e] = f2bf(v0 - bf2f(a));
        (&h1.x)[e] = bq; (&l1.x)[e] = f2bf(v1 - bf2f(bq));
    }
    *reinterpret_cast<ushort4*>(ao_hi + (size_t)bi * NX + lane * 4) = h0;
    *reinterpret_cast<ushort4*>(ao_lo + (size_t)bi * NX + lane * 4) = l0;
    *reinterpret_cast<ushort4*>(ao_hi + (size_t)bi * NX + 256 + lane * 4) = h1;
    *reinterpret_cast<ushort4*>(ao_lo + (size_t)bi * NX + 256 + lane * 4) = l1;
}

extern "C" void kernel_launch(void* const* d_in, const int* in_sizes, int n_in,
                              void* d_out, int out_size, void* d_ws, size_t ws_size,
                              hipStream_t stream)
{
    const float* x    = (const float*)d_in[0];
    const float* wq   = (const float*)d_in[1];
    const float* wk   = (const float*)d_in[2];
    const float* wv   = (const float*)d_in[3];
    const float* wo   = (const float*)d_in[4];
    const float* m1   = (const float*)d_in[5];
    const float* m2   = (const float*)d_in[6];
    const float* lq1  = (const float*)d_in[7];
    const float* lk1  = (const float*)d_in[8];
    const float* lq2  = (const float*)d_in[9];
    const float* lk2  = (const float*)d_in[10];
    const float* rmsg = (const float*)d_in[11];
    const int*   lint = (const int*)d_in[12];
    const int*   rns  = (const int*)d_in[14];
    const int*   lmk  = (const int*)d_in[15];
    float* out = (float*)d_out;
    float* ws  = (float*)d_ws;

    // ---- workspace layout ----
    const size_t M2 = 2097152;   // 2M
    float* q    = ws;                  // 2M f32
    float* k    = ws + M2;             // 2M
    float* v    = ws + 2 * M2;         // 2M
    float* w1   = ws + 3 * M2;         // 1M
    float* w2t  = ws + 3 * M2 + 1048576;
    float* cs   = ws + 4 * M2 + 1048576;         // 1024
    float* scal = cs + 1024;                      // small
    us* S = (us*)(cs + 2048);
    us* x_hi = S;                  // 2M shorts
    us* x_lo = S + M2;             // 2M
    us* ao_hi = x_hi;              // reuse (x split dead after QKV)
    us* ao_lo = x_lo;
    us* q_hi = S + 2 * M2;         // 2M
    us* q_lo = S + 3 * M2;
    us* k_hi = S + 4 * M2;
    us* k_lo = S + 5 * M2;
    us* wqkv_hi = S + 6 * M2;              // 786432
    us* wqkv_lo = wqkv_hi + 786432;
    us* wo_hi = wqkv_lo + 786432;          // 262144
    us* wo_lo = wo_hi + 262144;
    us* qn_hi = wo_lo + 262144;            // 65536 each
    us* qn_lo = qn_hi + 65536;
    us* kn_hi = qn_lo + 65536;
    us* kn_lo = kn_hi + 65536;

    k_prep<<<1, 64, 0, stream>>>(lq1, lk1, lq2, lk2, lint, scal);
    k_split_all<<<3072, 256, 0, stream>>>(x, wq, wk, wv, wo,
                                          x_hi, x_lo, wqkv_hi, wqkv_lo, wo_hi, wo_lo);

    // QKV fused: M=4096, N=1536 (q|k|v), K'=1536; also emits q/k bf16 splits
    k_gemm_big<128, true><<<dim3(64, 12), 256, 0, stream>>>(
        x_hi, x_lo, wqkv_hi, wqkv_lo, q, k, v, q_hi, q_lo, k_hi, k_lo);

    k_norm_lm<<<512, 64, 0, stream>>>(q, k, m1, m2, lmk, qn_hi, qn_lo, kn_hi, kn_lo);
    hipMemsetAsync(cs, 0, 1024 * sizeof(float), stream);
    k_colsum<<<dim3(4, 16), 256, 0, stream>>>(v, cs);
    k_gemm_w12<<<dim3(32, 8, 2), 256, 0, stream>>>(q_hi, q_lo, k_hi, k_lo,
                                                   kn_hi, kn_lo, qn_hi, qn_lo, w1, w2t);
    k_sparse_attn<<<1024, 256, 0, stream>>>(w1, w2t, v, cs, rns, rmsg, scal, ao_hi, ao_lo);

    // out = ao @ wo^T: M=4096, N=512, K'=1536
    k_gemm_big<64, false><<<dim3(64, 8), 256, 0, stream>>>(
        ao_hi, ao_lo, wo_hi, wo_lo, out, out, out, nullptr, nullptr, nullptr, nullptr);
}

// Round 5
// 157.773 us; speedup vs baseline: 2.1024x; 1.1227x over previous
//
#include <hip/hip_runtime.h>
#include <hip/hip_bf16.h>

// Problem constants
#define BB 2
#define TT 2048
#define NX 512
#define NH 4      // 2*H
#define HD 128
#define LL 64
#define KK 32

typedef __bf16 bf16x8 __attribute__((ext_vector_type(8)));
typedef float f32x4 __attribute__((ext_vector_type(4)));
typedef unsigned short us;
typedef const unsigned int __attribute__((address_space(1)))* gptr_t;
typedef unsigned int __attribute__((address_space(3)))* lptr_t;

__device__ __forceinline__ us f2bf(float f) {
    unsigned u = __float_as_uint(f);
    unsigned r = (u + 0x7fffu + ((u >> 16) & 1u)) >> 16;   // RNE
    return (us)r;
}
__device__ __forceinline__ float bf2f(us h) {
    return __uint_as_float(((unsigned)h) << 16);
}

// ---------------------------------------------------------------------------
// Fused: split f32 -> (hi,lo) bf16 for x,wq,wk,wv,wo  +  lam scalars (last blk)
// ---------------------------------------------------------------------------
__global__ void k_split_all(const float* __restrict__ x,
                            const float* __restrict__ wq, const float* __restrict__ wk,
                            const float* __restrict__ wv, const float* __restrict__ wo,
                            us* __restrict__ x_hi, us* __restrict__ x_lo,
                            us* __restrict__ wqkv_hi, us* __restrict__ wqkv_lo,
                            us* __restrict__ wo_hi, us* __restrict__ wo_lo,
                            const float* __restrict__ lq1, const float* __restrict__ lk1,
                            const float* __restrict__ lq2, const float* __restrict__ lk2,
                            const int* __restrict__ lint, float* __restrict__ scal)
{
    const int bidx = blockIdx.x;
    if (bidx == 3072) {                       // lam / lam_init scalars (1 wave)
        const int tid = threadIdx.x;
        if (tid < 64) {
            float s1 = lq1[tid] * lk1[tid] + lq1[tid + 64] * lk1[tid + 64];
            float s2 = lq2[tid] * lk2[tid] + lq2[tid + 64] * lk2[tid + 64];
            for (int off = 32; off; off >>= 1) { s1 += __shfl_xor(s1, off); s2 += __shfl_xor(s2, off); }
            if (tid == 0) {
                float lam_init = 0.8f - 0.6f * expf(-0.3f * (float)lint[0]);
                scal[0] = expf(s1) - expf(s2) + lam_init;
                scal[1] = lam_init;
            }
        }
        return;
    }
    const float* src;
    us* hi;
    us* lo;
    int pos;
    if (bidx < 2048) {
        src = x; hi = x_hi; lo = x_lo;
        pos = bidx * 1024 + threadIdx.x * 4;
    } else {
        const int w = (bidx - 2048) >> 8;          // 0..3
        const int p = (bidx - 2048) & 255;
        pos = p * 1024 + threadIdx.x * 4;
        if (w == 0)      { src = wq; hi = wqkv_hi;          lo = wqkv_lo; }
        else if (w == 1) { src = wk; hi = wqkv_hi + 262144; lo = wqkv_lo + 262144; }
        else if (w == 2) { src = wv; hi = wqkv_hi + 524288; lo = wqkv_lo + 524288; }
        else             { src = wo; hi = wo_hi;            lo = wo_lo; }
    }
    const float4 v = *reinterpret_cast<const float4*>(src + pos);
    ushort4 h, l;
    h.x = f2bf(v.x); l.x = f2bf(v.x - bf2f(h.x));
    h.y = f2bf(v.y); l.y = f2bf(v.y - bf2f(h.y));
    h.z = f2bf(v.z); l.z = f2bf(v.z - bf2f(h.z));
    h.w = f2bf(v.w); l.w = f2bf(v.w - bf2f(h.w));
    *reinterpret_cast<ushort4*>(hi + pos) = h;
    *reinterpret_cast<ushort4*>(lo + pos) = l;
}

// ---------------------------------------------------------------------------
// Split-bf16 MFMA GEMM, BM=64, BK=64, XOR-swizzled LDS (T2, both-sides form:
// pre-swizzled GLOBAL source column + linear global_load_lds dest + swizzled
// ds_read). MODE 0 (QKV): 3 segs (A hi,hi,lo ; B hi,lo,hi), N=1536 split into
// q|k|v regions; q,k emit bf16 hi/lo splits ONLY, v emits f32.
// MODE 1 (OUT): 2 segs (A hi,lo ; B hi,hi -> (a_hi+a_lo).b_hi), f32 out.
// ---------------------------------------------------------------------------
template<int BN, int MODE>
__global__ __launch_bounds__(256) void k_gemm_big(
    const us* __restrict__ a_hi, const us* __restrict__ a_lo,
    const us* __restrict__ b_hi, const us* __restrict__ b_lo,
    float* __restrict__ c2, float* __restrict__ cout,
    us* __restrict__ qs_hi, us* __restrict__ qs_lo,
    us* __restrict__ ks_hi, us* __restrict__ ks_lo)
{
    constexpr int NB = BN / 32;                 // frag cols per wave
    constexpr int NSTEP = (MODE == 0 ? 24 : 16);
    __shared__ us lsA[64 * 64];
    __shared__ us lsB[BN * 64];
    const int tid = threadIdx.x;
    const int m0 = blockIdx.x * 64, n0 = blockIdx.y * BN;
    const int region = n0 >> 9;                 // 0:q 1:k 2:v (MODE 0)
    const int ncol0 = n0 & 511;
    const int l = tid & 63, wid = tid >> 6;
    const int wr = (wid >> 1) * 32, wc = (wid & 1) * (BN / 2);
    const int lr = l & 15;
    const int lkb = (l >> 4) * 16;              // byte offset of lane's k-octet
    f32x4 acc[2][NB] = {};

    const int r8 = tid >> 3;                    // staging row 0..31
    const int swzc8 = (((tid & 7) ^ (r8 & 7)) * 8);  // pre-swizzled col (shorts)

    for (int kt = 0; kt < NSTEP; ++kt) {
        const int seg = kt >> 3;
        const int koff = (kt & 7) * 64;
        const us* ab;
        const us* bb;
        if constexpr (MODE == 0) {
            ab = (seg < 2 ? a_hi : a_lo) + koff + swzc8;
            bb = (seg == 1 ? b_lo : b_hi) + koff + swzc8;
        } else {
            ab = (seg == 0 ? a_hi : a_lo) + koff + swzc8;
            bb = b_hi + koff + swzc8;
        }
        #pragma unroll
        for (int j = 0; j < 2; ++j)
            __builtin_amdgcn_global_load_lds((gptr_t)(ab + (size_t)(m0 + j * 32 + r8) * 512),
                                             (lptr_t)(lsA + j * 2048 + tid * 8), 16, 0, 0);
        #pragma unroll
        for (int j = 0; j < BN / 32; ++j)
            __builtin_amdgcn_global_load_lds((gptr_t)(bb + (size_t)(n0 + j * 32 + r8) * 512),
                                             (lptr_t)(lsB + j * 2048 + tid * 8), 16, 0, 0);
        __syncthreads();   // barrier drains vmcnt -> LDS writes visible
        bf16x8 af[2][2], bfr[NB][2];
        #pragma unroll
        for (int m = 0; m < 2; ++m) {
            const int row = wr + m * 16 + lr;
            #pragma unroll
            for (int kk = 0; kk < 2; ++kk) {
                const int cb = (kk * 64 + lkb) ^ ((row & 7) << 4);
                af[m][kk] = *reinterpret_cast<const bf16x8*>(
                    (const char*)lsA + row * 128 + cb);
            }
        }
        #pragma unroll
        for (int n = 0; n < NB; ++n) {
            const int row = wc + n * 16 + lr;
            #pragma unroll
            for (int kk = 0; kk < 2; ++kk) {
                const int cb = (kk * 64 + lkb) ^ ((row & 7) << 4);
                bfr[n][kk] = *reinterpret_cast<const bf16x8*>(
                    (const char*)lsB + row * 128 + cb);
            }
        }
        #pragma unroll
        for (int kk = 0; kk < 2; ++kk)
            #pragma unroll
            for (int m = 0; m < 2; ++m)
                #pragma unroll
                for (int n = 0; n < NB; ++n)
                    acc[m][n] = __builtin_amdgcn_mfma_f32_16x16x32_bf16(
                        af[m][kk], bfr[n][kk], acc[m][n], 0, 0, 0);
        __syncthreads();
    }

    if constexpr (MODE == 0) {
        if (region < 2) {
            us* sh = (region == 0) ? qs_hi : ks_hi;
            us* slo = (region == 0) ? qs_lo : ks_lo;
            #pragma unroll
            for (int m = 0; m < 2; ++m) {
                const int row = m0 + wr + m * 16 + (l >> 4) * 4;
                #pragma unroll
                for (int n = 0; n < NB; ++n) {
                    const int col = ncol0 + wc + n * 16 + lr;
                    #pragma unroll
                    for (int r = 0; r < 4; ++r) {
                        const float val = acc[m][n][r];
                        const us h = f2bf(val);
                        sh[(size_t)(row + r) * 512 + col] = h;
                        slo[(size_t)(row + r) * 512 + col] = f2bf(val - bf2f(h));
                    }
                }
            }
        } else {
            #pragma unroll
            for (int m = 0; m < 2; ++m) {
                const int row = m0 + wr + m * 16 + (l >> 4) * 4;
                #pragma unroll
                for (int n = 0; n < NB; ++n) {
                    const int col = ncol0 + wc + n * 16 + lr;
                    #pragma unroll
                    for (int r = 0; r < 4; ++r)
                        c2[(size_t)(row + r) * 512 + col] = acc[m][n][r];
                }
            }
        }
    } else {
        #pragma unroll
        for (int m = 0; m < 2; ++m) {
            const int row = m0 + wr + m * 16 + (l >> 4) * 4;
            #pragma unroll
            for (int n = 0; n < NB; ++n) {
                const int col = n0 + wc + n * 16 + lr;
                #pragma unroll
                for (int r = 0; r < 4; ++r)
                    cout[(size_t)(row + r) * 512 + col] = acc[m][n][r];
            }
        }
    }
}

// ---------------------------------------------------------------------------
// w12 split-bf16 MFMA: BM=64, BN=64, K=128 (K'=384, 12 k-steps, BK=32).
// z=0: w1[bh,i,l] = q[b,i,h*128+:] . kn[bh,l,:]
// z=1: w2t[bh,j,l] = k[b,j,h*128+:] . qn[bh,l,:]
// ---------------------------------------------------------------------------
__global__ __launch_bounds__(256) void k_gemm_w12(
    const us* __restrict__ q_hi, const us* __restrict__ q_lo,
    const us* __restrict__ k_hi, const us* __restrict__ k_lo,
    const us* __restrict__ kn_hi, const us* __restrict__ kn_lo,
    const us* __restrict__ qn_hi, const us* __restrict__ qn_lo,
    float* __restrict__ w1, float* __restrict__ w2t)
{
    __shared__ us lsA[64 * 32];
    __shared__ us lsB[64 * 32];
    const int tid = threadIdx.x;
    const int m0 = blockIdx.x * 64;
    const int bh = blockIdx.y;                   // b*4+h
    const int h = bh & 3, b = bh >> 2;
    const int z = blockIdx.z;
    const us* ah = (z ? k_hi : q_hi) + ((size_t)b * 2048) * 512 + h * 128;
    const us* al = (z ? k_lo : q_lo) + ((size_t)b * 2048) * 512 + h * 128;
    const us* bh_p = (z ? qn_hi : kn_hi) + (size_t)bh * 64 * 128;
    const us* bl_p = (z ? qn_lo : kn_lo) + (size_t)bh * 64 * 128;
    float* C = (z ? w2t : w1) + (size_t)bh * 2048 * 64;

    const int l = tid & 63, wid = tid >> 6;
    const int wr = (wid >> 1) * 32, wc = (wid & 1) * 32;
    const int lr = l & 15, lk8 = (l >> 4) * 8;
    f32x4 acc[2][2] = {};
    const int srow = tid >> 2, scol = (tid & 3) * 8;

    for (int kt = 0; kt < 12; ++kt) {
        const int seg = kt >> 2;
        const int koff = (kt & 3) * 32;
        const us* ab = (seg < 2 ? ah : al) + koff + scol;
        const us* bb = (seg == 1 ? bl_p : bh_p) + koff + scol;
        __builtin_amdgcn_global_load_lds((gptr_t)(ab + (size_t)(m0 + srow) * 512),
                                         (lptr_t)(lsA + tid * 8), 16, 0, 0);
        __builtin_amdgcn_global_load_lds((gptr_t)(bb + (size_t)srow * 128),
                                         (lptr_t)(lsB + tid * 8), 16, 0, 0);
        __syncthreads();
        bf16x8 af[2], bfr[2];
        #pragma unroll
        for (int m = 0; m < 2; ++m)
            af[m] = *reinterpret_cast<const bf16x8*>(&lsA[(wr + m * 16 + lr) * 32 + lk8]);
        #pragma unroll
        for (int n = 0; n < 2; ++n)
            bfr[n] = *reinterpret_cast<const bf16x8*>(&lsB[(wc + n * 16 + lr) * 32 + lk8]);
        #pragma unroll
        for (int m = 0; m < 2; ++m)
            #pragma unroll
            for (int n = 0; n < 2; ++n)
                acc[m][n] = __builtin_amdgcn_mfma_f32_16x16x32_bf16(af[m], bfr[n], acc[m][n], 0, 0, 0);
        __syncthreads();
    }

    #pragma unroll
    for (int m = 0; m < 2; ++m) {
        const int row = m0 + wr + m * 16 + (l >> 4) * 4;
        #pragma unroll
        for (int n = 0; n < 2; ++n) {
            const int col = wc + n * 16 + lr;
            #pragma unroll
            for (int r = 0; r < 4; ++r)
                C[(size_t)(row + r) * 64 + col] = acc[m][n][r];
        }
    }
}

// Normalized landmark rows -> bf16 hi/lo splits (q/k reconstructed from splits).
__global__ void k_norm_lm(const us* __restrict__ q_hi, const us* __restrict__ q_lo,
                          const us* __restrict__ k_hi, const us* __restrict__ k_lo,
                          const float* __restrict__ m1, const float* __restrict__ m2,
                          const int* __restrict__ landmark,
                          us* __restrict__ qn_hi, us* __restrict__ qn_lo,
                          us* __restrict__ kn_hi, us* __restrict__ kn_lo)
{
    const int idx = blockIdx.x;              // B*NH*L = 512 blocks
    const int l = idx & 63;
    const int h = (idx >> 6) & 3;
    const int b = idx >> 8;
    const int lm = landmark[l];
    const int d = threadIdx.x;               // 64 threads = 1 wave

    const size_t qoff = ((size_t)(b * TT + lm)) * NX + h * HD;
    const float qa = bf2f(q_hi[qoff + d]) + bf2f(q_lo[qoff + d]);
    const float qb = bf2f(q_hi[qoff + d + 64]) + bf2f(q_lo[qoff + d + 64]);
    const float ka = bf2f(k_hi[qoff + d]) + bf2f(k_lo[qoff + d]);
    const float kb = bf2f(k_hi[qoff + d + 64]) + bf2f(k_lo[qoff + d + 64]);
    float sq = qa * qa + qb * qb;
    float sk = ka * ka + kb * kb;
    for (int off = 32; off; off >>= 1) { sq += __shfl_xor(sq, off); sk += __shfl_xor(sk, off); }
    const float invq = rsqrtf(sq) * m1[h * LL + l];
    const float invk = rsqrtf(sk) * m2[h * LL + l];
    const size_t base = (((size_t)(b * NH + h)) * LL + l) * HD;
    const float vq0 = qa * invq, vq1 = qb * invq;
    const float vk0 = ka * invk, vk1 = kb * invk;
    us h0;
    h0 = f2bf(vq0); qn_hi[base + d] = h0;      qn_lo[base + d] = f2bf(vq0 - bf2f(h0));
    h0 = f2bf(vq1); qn_hi[base + d + 64] = h0; qn_lo[base + d + 64] = f2bf(vq1 - bf2f(h0));
    h0 = f2bf(vk0); kn_hi[base + d] = h0;      kn_lo[base + d] = f2bf(vk0 - bf2f(h0));
    h0 = f2bf(vk1); kn_hi[base + d + 64] = h0; kn_lo[base + d + 64] = f2bf(vk1 - bf2f(h0));
}

// Column sums of V per batch: cs[b, e] = sum_t v[b,t,e]
__global__ void k_colsum(const float* __restrict__ v, float* __restrict__ cs)
{
    const int e = blockIdx.x * 256 + threadIdx.x;   // 0..1023
    const int b = e >> 9, c = e & 511;
    const int t0 = blockIdx.y * 128;
    const float* p = v + ((size_t)b) * TT * NX + c;
    float s = 0.f;
    for (int t = t0; t < t0 + 128; ++t) s += p[(size_t)t * NX];
    atomicAdd(&cs[e], s);
}

// ---------------------------------------------------------------------------
// Sparse masked softmax + wmix + PV + RMSNorm. ONE WAVE per (b, row i);
// wave-synchronous (no __syncthreads). 4 independent waves per block.
// ---------------------------------------------------------------------------
__global__ __launch_bounds__(256) void k_sparse_attn(
    const float* __restrict__ w1, const float* __restrict__ w2t,
    const float* __restrict__ v, const float* __restrict__ cs,
    const int* __restrict__ rns, const float* __restrict__ rms_g,
    const float* __restrict__ scal,
    us* __restrict__ ao_hi, us* __restrict__ ao_lo)
{
    const int wid = threadIdx.x >> 6;
    const int lane = threadIdx.x & 63;
    const int bi = blockIdx.x * 4 + wid;     // 0..4095
    const int b = bi >> 11, i = bi & 2047;

    __shared__ int   sl[4][32];
    __shared__ float plog[4][96];
    __shared__ float wmm[4][2][32];
    __shared__ float w1s[4][3][64];

    // candidates + dedup + symmetric check
    const int myidx = lane & 31;
    const int cand = rns[(size_t)bi * KK + myidx];
    int dup = 0;
    #pragma unroll
    for (int kk = 0; kk < 31; ++kk) {
        const int other = __shfl(cand, kk);
        dup |= (kk < myidx) & (other == cand);
    }
    const int* jrow = rns + ((size_t)(b * TT + cand)) * KK + (lane >> 5) * 16;
    int found = 0;
    #pragma unroll
    for (int kk = 0; kk < 16; ++kk) found |= (jrow[kk] == i);
    found |= __shfl_xor(found, 32);
    const int keep = (!dup) && found;
    const unsigned long long mask = __ballot(keep) & 0xffffffffull;
    const int sc = __popcll(mask);
    const int pos = __popcll(mask & ((1ull << myidx) - 1ull));
    if (lane < 32 && keep) sl[wid][pos] = cand;

    const float lam = scal[0], lam_init = scal[1];

    if (sc > 0) {
        // stage w1 rows (heads 1..3) for row i — only needed on this path
        #pragma unroll
        for (int r = 0; r < 3; ++r) {
            const int t = r * 64 + lane;
            const int hh = t >> 6, l2 = t & 63;
            w1s[wid][hh][l2] = w1[(((size_t)(b * NH + hh + 1)) * TT + i) * LL + l2];
        }
        // logits: tasks t = ss*3 + hh, 8 lanes per task
        const int ntask = 3 * sc;
        for (int t0 = 0; t0 < ntask; t0 += 8) {
            const int t = t0 + (lane >> 3);
            float part = 0.f;
            if (t < ntask) {
                const int hh = t % 3, ss = t / 3;
                const int j = sl[wid][ss];
                const float* w2row = w2t + (((size_t)(b * NH + hh + 1)) * TT + j) * LL + (lane & 7) * 8;
                const float* w1p = &w1s[wid][hh][(lane & 7) * 8];
                #pragma unroll
                for (int e = 0; e < 8; ++e) part += w1p[e] * w2row[e];
            }
            part += __shfl_xor(part, 1);
            part += __shfl_xor(part, 2);
            part += __shfl_xor(part, 4);
            if (t < ntask && (lane & 7) == 0) plog[wid][t] = part;
        }
        // per-head softmax over sc entries (3 lanes, sc typically 1-3)
        if (lane < 3) {
            float mx = -1e30f;
            for (int ss = 0; ss < sc; ++ss) mx = fmaxf(mx, plog[wid][ss * 3 + lane]);
            float s = 0.f;
            for (int ss = 0; ss < sc; ++ss) {
                const float e = expf(plog[wid][ss * 3 + lane] - mx);
                plog[wid][ss * 3 + lane] = e;
                s += e;
            }
            const float inv = 1.0f / s;
            for (int ss = 0; ss < sc; ++ss) plog[wid][ss * 3 + lane] *= inv;
        }
        if (lane < sc) {
            const float p1 = plog[wid][lane * 3 + 0];
            const float p2 = plog[wid][lane * 3 + 1];
            const float p3 = plog[wid][lane * 3 + 2];
            wmm[wid][0][lane] = (1.0f - lam) * p2 - lam * p1;
            wmm[wid][1][lane] = p2 - p1 + (1.0f - 2.0f * lam) * p3;
        }
    }

    // PV: each lane owns cols [lane*4, lane*4+4) of both 256-halves
    f32x4 acc0 = {0.f, 0.f, 0.f, 0.f}, acc1 = {0.f, 0.f, 0.f, 0.f};
    if (sc == 0) {
        const float cc = (1.0f - 2.0f * lam) * (1.0f / (float)TT);
        const f32x4 c0 = *reinterpret_cast<const f32x4*>(cs + b * NX + lane * 4);
        const f32x4 c1 = *reinterpret_cast<const f32x4*>(cs + b * NX + 256 + lane * 4);
        acc0 = cc * c0;
        acc1 = cc * c1;
    } else {
        for (int ss = 0; ss < sc; ++ss) {
            const float wa = wmm[wid][0][ss], wb = wmm[wid][1][ss];
            const float* vrow = v + ((size_t)(b * TT + sl[wid][ss])) * NX;
            const f32x4 va = *reinterpret_cast<const f32x4*>(vrow + lane * 4);
            const f32x4 vb = *reinterpret_cast<const f32x4*>(vrow + 256 + lane * 4);
            acc0 += wa * va;
            acc1 += wb * vb;
        }
    }

    // RMSNorm per half
    float s0 = acc0[0]*acc0[0] + acc0[1]*acc0[1] + acc0[2]*acc0[2] + acc0[3]*acc0[3];
    float s1 = acc1[0]*acc1[0] + acc1[1]*acc1[1] + acc1[2]*acc1[2] + acc1[3]*acc1[3];
    #pragma unroll
    for (int off = 32; off; off >>= 1) { s0 += __shfl_xor(s0, off); s1 += __shfl_xor(s1, off); }
    const float sc0 = rsqrtf(s0 * (1.0f / 256.0f) + 1e-5f);
    const float sc1 = rsqrtf(s1 * (1.0f / 256.0f) + 1e-5f);
    const float og = 1.0f - lam_init;
    // rms_g (256,) broadcasts over the last axis: BOTH halves use rms_g[e]
    const f32x4 g = *reinterpret_cast<const f32x4*>(rms_g + lane * 4);
    ushort4 h0, l0, h1, l1;
    #pragma unroll
    for (int e = 0; e < 4; ++e) {
        const float v0 = acc0[e] * sc0 * g[e] * og;
        const float v1 = acc1[e] * sc1 * g[e] * og;
        const us a = f2bf(v0);
        const us bq = f2bf(v1);
        (&h0.x)[e] = a;  (&l0.x)[e] = f2bf(v0 - bf2f(a));
        (&h1.x)[e] = bq; (&l1.x)[e] = f2bf(v1 - bf2f(bq));
    }
    *reinterpret_cast<ushort4*>(ao_hi + (size_t)bi * NX + lane * 4) = h0;
    *reinterpret_cast<ushort4*>(ao_lo + (size_t)bi * NX + lane * 4) = l0;
    *reinterpret_cast<ushort4*>(ao_hi + (size_t)bi * NX + 256 + lane * 4) = h1;
    *reinterpret_cast<ushort4*>(ao_lo + (size_t)bi * NX + 256 + lane * 4) = l1;
}

extern "C" void kernel_launch(void* const* d_in, const int* in_sizes, int n_in,
                              void* d_out, int out_size, void* d_ws, size_t ws_size,
                              hipStream_t stream)
{
    const float* x    = (const float*)d_in[0];
    const float* wq   = (const float*)d_in[1];
    const float* wk   = (const float*)d_in[2];
    const float* wv   = (const float*)d_in[3];
    const float* wo   = (const float*)d_in[4];
    const float* m1   = (const float*)d_in[5];
    const float* m2   = (const float*)d_in[6];
    const float* lq1  = (const float*)d_in[7];
    const float* lk1  = (const float*)d_in[8];
    const float* lq2  = (const float*)d_in[9];
    const float* lk2  = (const float*)d_in[10];
    const float* rmsg = (const float*)d_in[11];
    const int*   lint = (const int*)d_in[12];
    const int*   rns  = (const int*)d_in[14];
    const int*   lmk  = (const int*)d_in[15];
    float* out = (float*)d_out;
    float* ws  = (float*)d_ws;

    // ---- workspace layout ----
    const size_t M2 = 2097152;   // 2M elements
    float* v    = ws;                            // 2M f32
    float* w1   = ws + M2;                       // 1M f32
    float* w2t  = ws + M2 + 1048576;             // 1M f32
    float* cs   = ws + 2 * M2 + 1048576;         // 1024 f32
    float* scal = cs + 1024;
    us* S = (us*)(cs + 2048);
    us* x_hi = S;                  // 2M shorts each
    us* x_lo = S + M2;
    us* ao_hi = x_hi;              // reuse (x split dead after QKV)
    us* ao_lo = x_lo;
    us* q_hi = S + 2 * M2;
    us* q_lo = S + 3 * M2;
    us* k_hi = S + 4 * M2;
    us* k_lo = S + 5 * M2;
    us* wqkv_hi = S + 6 * M2;              // 786432
    us* wqkv_lo = wqkv_hi + 786432;
    us* wo_hi = wqkv_lo + 786432;          // 262144
    us* wo_lo = wo_hi + 262144;
    us* qn_hi = wo_lo + 262144;            // 65536 each
    us* qn_lo = qn_hi + 65536;
    us* kn_hi = qn_lo + 65536;
    us* kn_lo = kn_hi + 65536;

    k_split_all<<<3073, 256, 0, stream>>>(x, wq, wk, wv, wo,
                                          x_hi, x_lo, wqkv_hi, wqkv_lo, wo_hi, wo_lo,
                                          lq1, lk1, lq2, lk2, lint, scal);

    // QKV fused: M=4096, N=1536 (q|k|v), K'=1536; q/k emitted as bf16 splits, v f32
    k_gemm_big<128, 0><<<dim3(64, 12), 256, 0, stream>>>(
        x_hi, x_lo, wqkv_hi, wqkv_lo, v, nullptr, q_hi, q_lo, k_hi, k_lo);

    k_norm_lm<<<512, 64, 0, stream>>>(q_hi, q_lo, k_hi, k_lo, m1, m2, lmk,
                                      qn_hi, qn_lo, kn_hi, kn_lo);
    hipMemsetAsync(cs, 0, 1024 * sizeof(float), stream);
    k_colsum<<<dim3(4, 16), 256, 0, stream>>>(v, cs);
    k_gemm_w12<<<dim3(32, 8, 2), 256, 0, stream>>>(q_hi, q_lo, k_hi, k_lo,
                                                   kn_hi, kn_lo, qn_hi, qn_lo, w1, w2t);
    k_sparse_attn<<<1024, 256, 0, stream>>>(w1, w2t, v, cs, rns, rmsg, scal, ao_hi, ao_lo);

    // out = ao @ wo^T: M=4096, N=512, 2-term split (K'=1024)
    k_gemm_big<64, 1><<<dim3(64, 8), 256, 0, stream>>>(
        ao_hi, ao_lo, wo_hi, wo_lo, nullptr, out, nullptr, nullptr, nullptr, nullptr);
}

// Round 6
// 150.401 us; speedup vs baseline: 2.2054x; 1.0490x over previous
//
#include <hip/hip_runtime.h>
#include <hip/hip_bf16.h>

// Problem constants
#define BB 2
#define TT 2048
#define NX 512
#define NH 4      // 2*H
#define HD 128
#define LL 64
#define KK 32

typedef __bf16 bf16x8 __attribute__((ext_vector_type(8)));
typedef float f32x4 __attribute__((ext_vector_type(4)));
typedef unsigned short us;
typedef const unsigned int __attribute__((address_space(1)))* gptr_t;
typedef unsigned int __attribute__((address_space(3)))* lptr_t;

__device__ __forceinline__ us f2bf(float f) {
    unsigned u = __float_as_uint(f);
    unsigned r = (u + 0x7fffu + ((u >> 16) & 1u)) >> 16;   // RNE
    return (us)r;
}
__device__ __forceinline__ float bf2f(us h) {
    return __uint_as_float(((unsigned)h) << 16);
}

// ---------------------------------------------------------------------------
// Fused: split f32 -> (hi,lo) bf16 for x,wq,wk,wv,wo  +  lam scalars + cs zero
// ---------------------------------------------------------------------------
__global__ void k_split_all(const float* __restrict__ x,
                            const float* __restrict__ wq, const float* __restrict__ wk,
                            const float* __restrict__ wv, const float* __restrict__ wo,
                            us* __restrict__ x_hi, us* __restrict__ x_lo,
                            us* __restrict__ wqkv_hi, us* __restrict__ wqkv_lo,
                            us* __restrict__ wo_hi, us* __restrict__ wo_lo,
                            const float* __restrict__ lq1, const float* __restrict__ lk1,
                            const float* __restrict__ lq2, const float* __restrict__ lk2,
                            const int* __restrict__ lint, float* __restrict__ scal,
                            float* __restrict__ cs)
{
    const int bidx = blockIdx.x;
    if (bidx == 3072) {                       // lam scalars + cs zeroing
        const int tid = threadIdx.x;
        const f32x4 z = {0.f, 0.f, 0.f, 0.f};
        *reinterpret_cast<f32x4*>(cs + tid * 4) = z;   // 256*4 = 1024 floats
        if (tid < 64) {
            float s1 = lq1[tid] * lk1[tid] + lq1[tid + 64] * lk1[tid + 64];
            float s2 = lq2[tid] * lk2[tid] + lq2[tid + 64] * lk2[tid + 64];
            for (int off = 32; off; off >>= 1) { s1 += __shfl_xor(s1, off); s2 += __shfl_xor(s2, off); }
            if (tid == 0) {
                float lam_init = 0.8f - 0.6f * expf(-0.3f * (float)lint[0]);
                scal[0] = expf(s1) - expf(s2) + lam_init;
                scal[1] = lam_init;
            }
        }
        return;
    }
    const float* src;
    us* hi;
    us* lo;
    int pos;
    if (bidx < 2048) {
        src = x; hi = x_hi; lo = x_lo;
        pos = bidx * 1024 + threadIdx.x * 4;
    } else {
        const int w = (bidx - 2048) >> 8;          // 0..3
        const int p = (bidx - 2048) & 255;
        pos = p * 1024 + threadIdx.x * 4;
        if (w == 0)      { src = wq; hi = wqkv_hi;          lo = wqkv_lo; }
        else if (w == 1) { src = wk; hi = wqkv_hi + 262144; lo = wqkv_lo + 262144; }
        else if (w == 2) { src = wv; hi = wqkv_hi + 524288; lo = wqkv_lo + 524288; }
        else             { src = wo; hi = wo_hi;            lo = wo_lo; }
    }
    const float4 v = *reinterpret_cast<const float4*>(src + pos);
    ushort4 h, l;
    h.x = f2bf(v.x); l.x = f2bf(v.x - bf2f(h.x));
    h.y = f2bf(v.y); l.y = f2bf(v.y - bf2f(h.y));
    h.z = f2bf(v.z); l.z = f2bf(v.z - bf2f(h.z));
    h.w = f2bf(v.w); l.w = f2bf(v.w - bf2f(h.w));
    *reinterpret_cast<ushort4*>(hi + pos) = h;
    *reinterpret_cast<ushort4*>(lo + pos) = l;
}

// ---------------------------------------------------------------------------
// Split-bf16 MFMA GEMM, BM=64, BK=64, XOR-swizzled LDS (pre-swizzled GLOBAL
// source column + linear global_load_lds dest + swizzled ds_read).
// MODE 0 (QKV, BN=128): q/k regions (y 0..7): 3 segs A{hi,hi,lo} B{hi,lo,hi},
//   emit bf16 hi/lo splits; v region (y 8..11): 2 segs A{hi,lo} B{hi} -> bf16.
// MODE 1 (OUT, BN=64): 2 segs (a_hi+a_lo).b_hi, f32 out.
// ---------------------------------------------------------------------------
template<int BN, int MODE>
__global__ __launch_bounds__(256) void k_gemm_big(
    const us* __restrict__ a_hi, const us* __restrict__ a_lo,
    const us* __restrict__ b_hi, const us* __restrict__ b_lo,
    us* __restrict__ vb, float* __restrict__ cout,
    us* __restrict__ qs_hi, us* __restrict__ qs_lo,
    us* __restrict__ ks_hi, us* __restrict__ ks_lo)
{
    constexpr int NB = BN / 32;                 // frag cols per wave
    __shared__ us lsA[64 * 64];
    __shared__ us lsB[BN * 64];
    const int tid = threadIdx.x;
    const int m0 = blockIdx.x * 64, n0 = blockIdx.y * BN;
    const int region = n0 >> 9;                 // 0:q 1:k 2:v (MODE 0)
    const int ncol0 = n0 & 511;
    const int l = tid & 63, wid = tid >> 6;
    const int wr = (wid >> 1) * 32, wc = (wid & 1) * (BN / 2);
    const int lr = l & 15;
    const int lkb = (l >> 4) * 16;              // byte offset of lane's k-octet
    f32x4 acc[2][NB] = {};

    const int r8 = tid >> 3;                    // staging row 0..31
    const int swzc8 = (((tid & 7) ^ (r8 & 7)) * 8);  // pre-swizzled col (shorts)

    const int nstep = (MODE == 0) ? (region < 2 ? 24 : 16) : 16;
    for (int kt = 0; kt < nstep; ++kt) {
        const int seg = kt >> 3;
        const int koff = (kt & 7) * 64;
        const us* ab;
        const us* bb;
        if constexpr (MODE == 0) {
            if (region < 2) {
                ab = (seg < 2 ? a_hi : a_lo) + koff + swzc8;
                bb = (seg == 1 ? b_lo : b_hi) + koff + swzc8;
            } else {   // v: (a_hi + a_lo) . b_hi
                ab = (seg == 0 ? a_hi : a_lo) + koff + swzc8;
                bb = b_hi + koff + swzc8;
            }
        } else {
            ab = (seg == 0 ? a_hi : a_lo) + koff + swzc8;
            bb = b_hi + koff + swzc8;
        }
        #pragma unroll
        for (int j = 0; j < 2; ++j)
            __builtin_amdgcn_global_load_lds((gptr_t)(ab + (size_t)(m0 + j * 32 + r8) * 512),
                                             (lptr_t)(lsA + j * 2048 + tid * 8), 16, 0, 0);
        #pragma unroll
        for (int j = 0; j < BN / 32; ++j)
            __builtin_amdgcn_global_load_lds((gptr_t)(bb + (size_t)(n0 + j * 32 + r8) * 512),
                                             (lptr_t)(lsB + j * 2048 + tid * 8), 16, 0, 0);
        __syncthreads();   // barrier drains vmcnt -> LDS writes visible
        bf16x8 af[2][2], bfr[NB][2];
        #pragma unroll
        for (int m = 0; m < 2; ++m) {
            const int row = wr + m * 16 + lr;
            #pragma unroll
            for (int kk = 0; kk < 2; ++kk) {
                const int cb = (kk * 64 + lkb) ^ ((row & 7) << 4);
                af[m][kk] = *reinterpret_cast<const bf16x8*>(
                    (const char*)lsA + row * 128 + cb);
            }
        }
        #pragma unroll
        for (int n = 0; n < NB; ++n) {
            const int row = wc + n * 16 + lr;
            #pragma unroll
            for (int kk = 0; kk < 2; ++kk) {
                const int cb = (kk * 64 + lkb) ^ ((row & 7) << 4);
                bfr[n][kk] = *reinterpret_cast<const bf16x8*>(
                    (const char*)lsB + row * 128 + cb);
            }
        }
        #pragma unroll
        for (int kk = 0; kk < 2; ++kk)
            #pragma unroll
            for (int m = 0; m < 2; ++m)
                #pragma unroll
                for (int n = 0; n < NB; ++n)
                    acc[m][n] = __builtin_amdgcn_mfma_f32_16x16x32_bf16(
                        af[m][kk], bfr[n][kk], acc[m][n], 0, 0, 0);
        __syncthreads();
    }

    if constexpr (MODE == 0) {
        if (region < 2) {
            us* sh = (region == 0) ? qs_hi : ks_hi;
            us* slo = (region == 0) ? qs_lo : ks_lo;
            #pragma unroll
            for (int m = 0; m < 2; ++m) {
                const int row = m0 + wr + m * 16 + (l >> 4) * 4;
                #pragma unroll
                for (int n = 0; n < NB; ++n) {
                    const int col = ncol0 + wc + n * 16 + lr;
                    #pragma unroll
                    for (int r = 0; r < 4; ++r) {
                        const float val = acc[m][n][r];
                        const us h = f2bf(val);
                        sh[(size_t)(row + r) * 512 + col] = h;
                        slo[(size_t)(row + r) * 512 + col] = f2bf(val - bf2f(h));
                    }
                }
            }
        } else {
            #pragma unroll
            for (int m = 0; m < 2; ++m) {
                const int row = m0 + wr + m * 16 + (l >> 4) * 4;
                #pragma unroll
                for (int n = 0; n < NB; ++n) {
                    const int col = ncol0 + wc + n * 16 + lr;
                    #pragma unroll
                    for (int r = 0; r < 4; ++r)
                        vb[(size_t)(row + r) * 512 + col] = f2bf(acc[m][n][r]);
                }
            }
        }
    } else {
        #pragma unroll
        for (int m = 0; m < 2; ++m) {
            const int row = m0 + wr + m * 16 + (l >> 4) * 4;
            #pragma unroll
            for (int n = 0; n < NB; ++n) {
                const int col = n0 + wc + n * 16 + lr;
                #pragma unroll
                for (int r = 0; r < 4; ++r)
                    cout[(size_t)(row + r) * 512 + col] = acc[m][n][r];
            }
        }
    }
}

// ---------------------------------------------------------------------------
// w12 split-bf16 MFMA: BM=64, BN=64, K=128 (K'=384, 12 k-steps, BK=32).
// HEADS 1..3 ONLY (head 0 cancels from wmix). Compact layout [b][hh=h-1][T][64].
// z=0: w1[b,hh,i,l] = q[b,i,(hh+1)*128+:] . kn[b*4+hh+1,l,:]
// z=1: w2t[b,hh,j,l] = k[b,j,(hh+1)*128+:] . qn[b*4+hh+1,l,:]
// ---------------------------------------------------------------------------
__global__ __launch_bounds__(256) void k_gemm_w12(
    const us* __restrict__ q_hi, const us* __restrict__ q_lo,
    const us* __restrict__ k_hi, const us* __restrict__ k_lo,
    const us* __restrict__ kn_hi, const us* __restrict__ kn_lo,
    const us* __restrict__ qn_hi, const us* __restrict__ qn_lo,
    float* __restrict__ w1, float* __restrict__ w2t)
{
    __shared__ us lsA[64 * 32];
    __shared__ us lsB[64 * 32];
    const int tid = threadIdx.x;
    const int m0 = blockIdx.x * 64;
    const int y = blockIdx.y;                    // 0..5
    const int hh = y % 3, b = y / 3;             // hh 0..2 -> head hh+1
    const int h = hh + 1;
    const int z = blockIdx.z;
    const us* ah = (z ? k_hi : q_hi) + ((size_t)b * 2048) * 512 + h * 128;
    const us* al = (z ? k_lo : q_lo) + ((size_t)b * 2048) * 512 + h * 128;
    const us* bh_p = (z ? qn_hi : kn_hi) + (size_t)(b * 4 + h) * 64 * 128;
    const us* bl_p = (z ? qn_lo : kn_lo) + (size_t)(b * 4 + h) * 64 * 128;
    float* C = (z ? w2t : w1) + (size_t)(b * 3 + hh) * 2048 * 64;

    const int l = tid & 63, wid = tid >> 6;
    const int wr = (wid >> 1) * 32, wc = (wid & 1) * 32;
    const int lr = l & 15, lk8 = (l >> 4) * 8;
    f32x4 acc[2][2] = {};
    const int srow = tid >> 2, scol = (tid & 3) * 8;

    for (int kt = 0; kt < 12; ++kt) {
        const int seg = kt >> 2;
        const int koff = (kt & 3) * 32;
        const us* ab = (seg < 2 ? ah : al) + koff + scol;
        const us* bb = (seg == 1 ? bl_p : bh_p) + koff + scol;
        __builtin_amdgcn_global_load_lds((gptr_t)(ab + (size_t)(m0 + srow) * 512),
                                         (lptr_t)(lsA + tid * 8), 16, 0, 0);
        __builtin_amdgcn_global_load_lds((gptr_t)(bb + (size_t)srow * 128),
                                         (lptr_t)(lsB + tid * 8), 16, 0, 0);
        __syncthreads();
        bf16x8 af[2], bfr[2];
        #pragma unroll
        for (int m = 0; m < 2; ++m)
            af[m] = *reinterpret_cast<const bf16x8*>(&lsA[(wr + m * 16 + lr) * 32 + lk8]);
        #pragma unroll
        for (int n = 0; n < 2; ++n)
            bfr[n] = *reinterpret_cast<const bf16x8*>(&lsB[(wc + n * 16 + lr) * 32 + lk8]);
        #pragma unroll
        for (int m = 0; m < 2; ++m)
            #pragma unroll
            for (int n = 0; n < 2; ++n)
                acc[m][n] = __builtin_amdgcn_mfma_f32_16x16x32_bf16(af[m], bfr[n], acc[m][n], 0, 0, 0);
        __syncthreads();
    }

    #pragma unroll
    for (int m = 0; m < 2; ++m) {
        const int row = m0 + wr + m * 16 + (l >> 4) * 4;
        #pragma unroll
        for (int n = 0; n < 2; ++n) {
            const int col = wc + n * 16 + lr;
            #pragma unroll
            for (int r = 0; r < 4; ++r)
                C[(size_t)(row + r) * 64 + col] = acc[m][n][r];
        }
    }
}

// Normalized landmark rows -> bf16 hi/lo splits (q/k reconstructed from splits).
__global__ void k_norm_lm(const us* __restrict__ q_hi, const us* __restrict__ q_lo,
                          const us* __restrict__ k_hi, const us* __restrict__ k_lo,
                          const float* __restrict__ m1, const float* __restrict__ m2,
                          const int* __restrict__ landmark,
                          us* __restrict__ qn_hi, us* __restrict__ qn_lo,
                          us* __restrict__ kn_hi, us* __restrict__ kn_lo)
{
    const int idx = blockIdx.x;              // B*NH*L = 512 blocks
    const int l = idx & 63;
    const int h = (idx >> 6) & 3;
    const int b = idx >> 8;
    const int lm = landmark[l];
    const int d = threadIdx.x;               // 64 threads = 1 wave

    const size_t qoff = ((size_t)(b * TT + lm)) * NX + h * HD;
    const float qa = bf2f(q_hi[qoff + d]) + bf2f(q_lo[qoff + d]);
    const float qb = bf2f(q_hi[qoff + d + 64]) + bf2f(q_lo[qoff + d + 64]);
    const float ka = bf2f(k_hi[qoff + d]) + bf2f(k_lo[qoff + d]);
    const float kb = bf2f(k_hi[qoff + d + 64]) + bf2f(k_lo[qoff + d + 64]);
    float sq = qa * qa + qb * qb;
    float sk = ka * ka + kb * kb;
    for (int off = 32; off; off >>= 1) { sq += __shfl_xor(sq, off); sk += __shfl_xor(sk, off); }
    const float invq = rsqrtf(sq) * m1[h * LL + l];
    const float invk = rsqrtf(sk) * m2[h * LL + l];
    const size_t base = (((size_t)(b * NH + h)) * LL + l) * HD;
    const float vq0 = qa * invq, vq1 = qb * invq;
    const float vk0 = ka * invk, vk1 = kb * invk;
    us h0;
    h0 = f2bf(vq0); qn_hi[base + d] = h0;      qn_lo[base + d] = f2bf(vq0 - bf2f(h0));
    h0 = f2bf(vq1); qn_hi[base + d + 64] = h0; qn_lo[base + d + 64] = f2bf(vq1 - bf2f(h0));
    h0 = f2bf(vk0); kn_hi[base + d] = h0;      kn_lo[base + d] = f2bf(vk0 - bf2f(h0));
    h0 = f2bf(vk1); kn_hi[base + d + 64] = h0; kn_lo[base + d + 64] = f2bf(vk1 - bf2f(h0));
}

// Column sums of bf16 V: cs[b*512+c] = sum_t v[b,t,c].  32 blocks x 64 rows.
__global__ void k_colsum(const us* __restrict__ vb, float* __restrict__ cs)
{
    const int tid = threadIdx.x;             // 256
    const int c4 = tid * 4;                  // 0..1023 (b*512 + c)
    const int b = c4 >> 9, c = c4 & 511;
    const int t0 = blockIdx.x * 64;
    const us* p = vb + ((size_t)(b * TT + t0)) * NX + c;
    f32x4 s = {0.f, 0.f, 0.f, 0.f};
    for (int t = 0; t < 64; ++t) {
        const ushort4 u = *reinterpret_cast<const ushort4*>(p + (size_t)t * NX);
        s[0] += bf2f(u.x); s[1] += bf2f(u.y); s[2] += bf2f(u.z); s[3] += bf2f(u.w);
    }
    atomicAdd(&cs[c4 + 0], s[0]);
    atomicAdd(&cs[c4 + 1], s[1]);
    atomicAdd(&cs[c4 + 2], s[2]);
    atomicAdd(&cs[c4 + 3], s[3]);
}

// ---------------------------------------------------------------------------
// Sparse masked softmax + wmix + PV + RMSNorm. ONE WAVE per (b, row i);
// wave-synchronous. 4 independent waves per block. V is bf16.
// w1/w2t compact: [b][hh=head-1][T][64].
// ---------------------------------------------------------------------------
__global__ __launch_bounds__(256) void k_sparse_attn(
    const float* __restrict__ w1, const float* __restrict__ w2t,
    const us* __restrict__ vb, const float* __restrict__ cs,
    const int* __restrict__ rns, const float* __restrict__ rms_g,
    const float* __restrict__ scal,
    us* __restrict__ ao_hi, us* __restrict__ ao_lo)
{
    const int wid = threadIdx.x >> 6;
    const int lane = threadIdx.x & 63;
    const int bi = blockIdx.x * 4 + wid;     // 0..4095
    const int b = bi >> 11, i = bi & 2047;

    __shared__ int   sl[4][32];
    __shared__ float plog[4][96];
    __shared__ float wmm[4][2][32];
    __shared__ float w1s[4][3][64];

    // candidates + dedup + symmetric check
    const int myidx = lane & 31;
    const int cand = rns[(size_t)bi * KK + myidx];
    int dup = 0;
    #pragma unroll
    for (int kk = 0; kk < 31; ++kk) {
        const int other = __shfl(cand, kk);
        dup |= (kk < myidx) & (other == cand);
    }
    const int* jrow = rns + ((size_t)(b * TT + cand)) * KK + (lane >> 5) * 16;
    int found = 0;
    #pragma unroll
    for (int kk = 0; kk < 16; ++kk) found |= (jrow[kk] == i);
    found |= __shfl_xor(found, 32);
    const int keep = (!dup) && found;
    const unsigned long long mask = __ballot(keep) & 0xffffffffull;
    const int sc = __popcll(mask);
    const int pos = __popcll(mask & ((1ull << myidx) - 1ull));
    if (lane < 32 && keep) sl[wid][pos] = cand;

    const float lam = scal[0], lam_init = scal[1];

    if (sc > 0) {
        // stage w1 rows (heads 1..3 compact) for row i
        #pragma unroll
        for (int r = 0; r < 3; ++r) {
            const int t = r * 64 + lane;
            const int hh = t >> 6, l2 = t & 63;
            w1s[wid][hh][l2] = w1[(((size_t)(b * 3 + hh)) * TT + i) * LL + l2];
        }
        // logits: tasks t = ss*3 + hh, 8 lanes per task
        const int ntask = 3 * sc;
        for (int t0 = 0; t0 < ntask; t0 += 8) {
            const int t = t0 + (lane >> 3);
            float part = 0.f;
            if (t < ntask) {
                const int hh = t % 3, ss = t / 3;
                const int j = sl[wid][ss];
                const float* w2row = w2t + (((size_t)(b * 3 + hh)) * TT + j) * LL + (lane & 7) * 8;
                const float* w1p = &w1s[wid][hh][(lane & 7) * 8];
                #pragma unroll
                for (int e = 0; e < 8; ++e) part += w1p[e] * w2row[e];
            }
            part += __shfl_xor(part, 1);
            part += __shfl_xor(part, 2);
            part += __shfl_xor(part, 4);
            if (t < ntask && (lane & 7) == 0) plog[wid][t] = part;
        }
        // per-head softmax over sc entries
        if (lane < 3) {
            float mx = -1e30f;
            for (int ss = 0; ss < sc; ++ss) mx = fmaxf(mx, plog[wid][ss * 3 + lane]);
            float s = 0.f;
            for (int ss = 0; ss < sc; ++ss) {
                const float e = expf(plog[wid][ss * 3 + lane] - mx);
                plog[wid][ss * 3 + lane] = e;
                s += e;
            }
            const float inv = 1.0f / s;
            for (int ss = 0; ss < sc; ++ss) plog[wid][ss * 3 + lane] *= inv;
        }
        if (lane < sc) {
            const float p1 = plog[wid][lane * 3 + 0];
            const float p2 = plog[wid][lane * 3 + 1];
            const float p3 = plog[wid][lane * 3 + 2];
            wmm[wid][0][lane] = (1.0f - lam) * p2 - lam * p1;
            wmm[wid][1][lane] = p2 - p1 + (1.0f - 2.0f * lam) * p3;
        }
    }

    // PV: each lane owns cols [lane*4, lane*4+4) of both 256-halves
    f32x4 acc0 = {0.f, 0.f, 0.f, 0.f}, acc1 = {0.f, 0.f, 0.f, 0.f};
    if (sc == 0) {
        const float cc = (1.0f - 2.0f * lam) * (1.0f / (float)TT);
        const f32x4 c0 = *reinterpret_cast<const f32x4*>(cs + b * NX + lane * 4);
        const f32x4 c1 = *reinterpret_cast<const f32x4*>(cs + b * NX + 256 + lane * 4);
        acc0 = cc * c0;
        acc1 = cc * c1;
    } else {
        for (int ss = 0; ss < sc; ++ss) {
            const float wa = wmm[wid][0][ss], wb = wmm[wid][1][ss];
            const us* vrow = vb + ((size_t)(b * TT + sl[wid][ss])) * NX;
            const ushort4 ua = *reinterpret_cast<const ushort4*>(vrow + lane * 4);
            const ushort4 ub = *reinterpret_cast<const ushort4*>(vrow + 256 + lane * 4);
            acc0[0] += wa * bf2f(ua.x); acc0[1] += wa * bf2f(ua.y);
            acc0[2] += wa * bf2f(ua.z); acc0[3] += wa * bf2f(ua.w);
            acc1[0] += wb * bf2f(ub.x); acc1[1] += wb * bf2f(ub.y);
            acc1[2] += wb * bf2f(ub.z); acc1[3] += wb * bf2f(ub.w);
        }
    }

    // RMSNorm per half
    float s0 = acc0[0]*acc0[0] + acc0[1]*acc0[1] + acc0[2]*acc0[2] + acc0[3]*acc0[3];
    float s1 = acc1[0]*acc1[0] + acc1[1]*acc1[1] + acc1[2]*acc1[2] + acc1[3]*acc1[3];
    #pragma unroll
    for (int off = 32; off; off >>= 1) { s0 += __shfl_xor(s0, off); s1 += __shfl_xor(s1, off); }
    const float sc0 = rsqrtf(s0 * (1.0f / 256.0f) + 1e-5f);
    const float sc1 = rsqrtf(s1 * (1.0f / 256.0f) + 1e-5f);
    const float og = 1.0f - lam_init;
    // rms_g (256,) broadcasts over the last axis: BOTH halves use rms_g[e]
    const f32x4 g = *reinterpret_cast<const f32x4*>(rms_g + lane * 4);
    ushort4 h0, l0, h1, l1;
    #pragma unroll
    for (int e = 0; e < 4; ++e) {
        const float v0 = acc0[e] * sc0 * g[e] * og;
        const float v1 = acc1[e] * sc1 * g[e] * og;
        const us a = f2bf(v0);
        const us bq = f2bf(v1);
        (&h0.x)[e] = a;  (&l0.x)[e] = f2bf(v0 - bf2f(a));
        (&h1.x)[e] = bq; (&l1.x)[e] = f2bf(v1 - bf2f(bq));
    }
    *reinterpret_cast<ushort4*>(ao_hi + (size_t)bi * NX + lane * 4) = h0;
    *reinterpret_cast<ushort4*>(ao_lo + (size_t)bi * NX + lane * 4) = l0;
    *reinterpret_cast<ushort4*>(ao_hi + (size_t)bi * NX + 256 + lane * 4) = h1;
    *reinterpret_cast<ushort4*>(ao_lo + (size_t)bi * NX + 256 + lane * 4) = l1;
}

extern "C" void kernel_launch(void* const* d_in, const int* in_sizes, int n_in,
                              void* d_out, int out_size, void* d_ws, size_t ws_size,
                              hipStream_t stream)
{
    const float* x    = (const float*)d_in[0];
    const float* wq   = (const float*)d_in[1];
    const float* wk   = (const float*)d_in[2];
    const float* wv   = (const float*)d_in[3];
    const float* wo   = (const float*)d_in[4];
    const float* m1   = (const float*)d_in[5];
    const float* m2   = (const float*)d_in[6];
    const float* lq1  = (const float*)d_in[7];
    const float* lk1  = (const float*)d_in[8];
    const float* lq2  = (const float*)d_in[9];
    const float* lk2  = (const float*)d_in[10];
    const float* rmsg = (const float*)d_in[11];
    const int*   lint = (const int*)d_in[12];
    const int*   rns  = (const int*)d_in[14];
    const int*   lmk  = (const int*)d_in[15];
    float* out = (float*)d_out;
    float* ws  = (float*)d_ws;

    // ---- workspace layout ----
    const size_t M2 = 2097152;   // 2M elements
    const size_t W3 = 786432;    // 3 heads x 2048 x 64 x 2 batches / 2... (b*3+hh)*2048*64, 6*131072
    float* w1   = ws;                        // 786,432 f32
    float* w2t  = ws + W3;                   // 786,432 f32
    float* cs   = ws + 2 * W3;               // 1,024 f32
    float* scal = cs + 1024;                 // small (pad 128)
    us* S = (us*)(scal + 128);
    us* vb   = S;                  // 2M us (bf16 V)
    us* x_hi = S + M2;             // 2M each
    us* x_lo = S + 2 * M2;
    us* ao_hi = x_hi;              // reuse (x split dead after QKV)
    us* ao_lo = x_lo;
    us* q_hi = S + 3 * M2;
    us* q_lo = S + 4 * M2;
    us* k_hi = S + 5 * M2;
    us* k_lo = S + 6 * M2;
    us* wqkv_hi = S + 7 * M2;              // 786,432
    us* wqkv_lo = wqkv_hi + 786432;
    us* wo_hi = wqkv_lo + 786432;          // 262,144
    us* wo_lo = wo_hi + 262144;
    us* qn_hi = wo_lo + 262144;            // 65,536 each
    us* qn_lo = qn_hi + 65536;
    us* kn_hi = qn_lo + 65536;
    us* kn_lo = kn_hi + 65536;

    k_split_all<<<3073, 256, 0, stream>>>(x, wq, wk, wv, wo,
                                          x_hi, x_lo, wqkv_hi, wqkv_lo, wo_hi, wo_lo,
                                          lq1, lk1, lq2, lk2, lint, scal, cs);

    // QKV fused: M=4096, N=1536 (q|k|v); q/k 3-term -> bf16 splits, v 2-term -> bf16
    k_gemm_big<128, 0><<<dim3(64, 12), 256, 0, stream>>>(
        x_hi, x_lo, wqkv_hi, wqkv_lo, vb, nullptr, q_hi, q_lo, k_hi, k_lo);

    k_norm_lm<<<512, 64, 0, stream>>>(q_hi, q_lo, k_hi, k_lo, m1, m2, lmk,
                                      qn_hi, qn_lo, kn_hi, kn_lo);
    k_colsum<<<32, 256, 0, stream>>>(vb, cs);
    k_gemm_w12<<<dim3(32, 6, 2), 256, 0, stream>>>(q_hi, q_lo, k_hi, k_lo,
                                                   kn_hi, kn_lo, qn_hi, qn_lo, w1, w2t);
    k_sparse_attn<<<1024, 256, 0, stream>>>(w1, w2t, vb, cs, rns, rmsg, scal, ao_hi, ao_lo);

    // out = ao @ wo^T: M=4096, N=512, 2-term split (K'=1024)
    k_gemm_big<64, 1><<<dim3(64, 8), 256, 0, stream>>>(
        ao_hi, ao_lo, wo_hi, wo_lo, nullptr, out, nullptr, nullptr, nullptr, nullptr);
}